// Round 9
// baseline (164.046 us; speedup 1.0000x reference)
//
#include <hip/hip_runtime.h>
#include <hip/hip_bf16.h>
#include <stdint.h>

#define N_NODES 50000
#define N_EDGES 800000
#define IN_CH   128
#define NEG_SLOPE 0.2f

// ---- radix CSR build (R7 geometry, verified) ----
#define NBUCK   196              // bucket = tgt>>8 (256 nodes per bucket)
#define E1      4000             // edges per pass-1 block (16KB LDS, 8 blocks/CU)
#define FILLB   200              // 800000 / 4000
#define BCAP    6144             // u32 records per bucket region (24576/4)
#define BSTRIDE 24576            // bytes per bucket region == 256*48*2 (csr overlay)
#define CAPR    48               // csr slots per node (Poisson(16): P(deg>48)*N ~ 5e-11)

// ---- legacy fallback (R4) ----
#define E_PER 8
#define FILL_BLOCKS 391

typedef short short8 __attribute__((ext_vector_type(8)));
typedef float f32x4  __attribute__((ext_vector_type(4)));
typedef float f32x2  __attribute__((ext_vector_type(2)));

static __device__ __forceinline__ float bf_lo(uint32_t p) { return __uint_as_float(p << 16); }
static __device__ __forceinline__ float bf_hi(uint32_t p) { return __uint_as_float(p & 0xffff0000u); }
static __device__ __forceinline__ uint16_t f_to_bf(float f) {
    uint32_t u = __float_as_uint(f);
    u += 0x7fffu + ((u >> 16) & 1u);   // round-to-nearest-even
    return (uint16_t)(u >> 16);
}

// leaky-relu on a packed pair
static __device__ __forceinline__ f32x2 lrelu2(f32x2 x) {
    f32x2 s = x * NEG_SLOPE;
    f32x2 r;
    r[0] = fmaxf(x[0], s[0]);
    r[1] = fmaxf(x[1], s[1]);
    return r;
}

// single DPP add step (compiler handles hazards for the builtin form)
#define DPPADD(x, ctrl) __uint_as_float(__builtin_amdgcn_update_dpp(0, __float_as_uint(x), ctrl, 0xf, 0xf, true))

// ---------------------------------------------------------------------------
// Shared bodies
// ---------------------------------------------------------------------------
static __device__ __forceinline__ void wswz_body(
    int t, const float* __restrict__ Wl, const float* __restrict__ Wr,
    __hip_bfloat16* __restrict__ wswz)
{
    int ct = t >> 8, rem = t & 255;
    int ch = rem >> 6, lane = rem & 63;
    int m = lane & 15, quad = lane >> 4;
    const float* W = (ct < 8) ? Wl : Wr;
    int o = ((ct & 7) << 4) + m;
    const float* src = W + (size_t)o * IN_CH + ch * 32 + quad * 8;
    short8 f;
#pragma unroll
    for (int j = 0; j < 8; ++j) f[j] = (short)f_to_bf(src[j]);
    *(short8*)((short*)wswz + (size_t)t * 8) = f;
}

// proj: 4 waves per block share one 16-row group; wave w does ct in [4w,4w+4).
// XLBF: xl stored as bf16 (radix mode) or f32 (legacy: xl lives in d_out).
template<bool XLBF>
static __device__ __forceinline__ void proj_body(
    int rowbase, int tid,
    const float* __restrict__ x, const __hip_bfloat16* __restrict__ wswz,
    const float* __restrict__ bl, const float* __restrict__ br,
    void* __restrict__ xl, __hip_bfloat16* __restrict__ xr)
{
    int lane = tid & 63;
    int widx = tid >> 6;              // 0..3: ct group
    int m = lane & 15;
    int quad = lane >> 4;

    short8 afrag[4];
    const float* xrow = x + (size_t)(rowbase + m) * IN_CH;
#pragma unroll
    for (int ch = 0; ch < 4; ++ch) {
        f32x4 p0 = *(const f32x4*)(xrow + ch * 32 + quad * 8);
        f32x4 p1 = *(const f32x4*)(xrow + ch * 32 + quad * 8 + 4);
        short8 f;
#pragma unroll
        for (int j = 0; j < 4; ++j) { f[j] = (short)f_to_bf(p0[j]); f[j + 4] = (short)f_to_bf(p1[j]); }
        afrag[ch] = f;
    }

    const short* wz = (const short*)wswz;
    const float* bv = (widx < 2) ? bl : br;   // wave-uniform
#pragma unroll
    for (int cc = 0; cc < 4; ++cc) {
        int ct = widx * 4 + cc;
        int o = ((ct & 7) << 4) + m;
        f32x4 acc = {0.f, 0.f, 0.f, 0.f};
#pragma unroll
        for (int ch = 0; ch < 4; ++ch) {
            short8 bfrag = *(const short8*)(wz + ((size_t)(ct * 4 + ch) * 64 + lane) * 8);
            acc = __builtin_amdgcn_mfma_f32_16x16x32_bf16(afrag[ch], bfrag, acc, 0, 0, 0);
        }
        float bias_v = bv[o];
        // D layout: row = quad*4 + r, col = m   [m89-verified]
        if (widx < 2) {
#pragma unroll
            for (int r = 0; r < 4; ++r) {
                size_t idx = (size_t)(rowbase + quad * 4 + r) * IN_CH + o;
                if constexpr (XLBF)
                    ((__hip_bfloat16*)xl)[idx] = __float2bfloat16(acc[r] + bias_v);
                else
                    ((float*)xl)[idx] = acc[r] + bias_v;
            }
        } else {
#pragma unroll
            for (int r = 0; r < 4; ++r)
                xr[(size_t)(rowbase + quad * 4 + r) * IN_CH + o] = __float2bfloat16(acc[r] + bias_v);
        }
    }
}

// ---------------------------------------------------------------------------
// prep: wswz swizzle + zero zn ints at z (bucket counters OR legacy cnt).
// ---------------------------------------------------------------------------
__global__ __launch_bounds__(256) void prep_kernel(
    const float* __restrict__ Wl, const float* __restrict__ Wr,
    __hip_bfloat16* __restrict__ wswz, int* __restrict__ z, int zn)
{
    int t = blockIdx.x * 256 + threadIdx.x;
    if (t < 4096) wswz_body(t, Wl, Wr, wswz);
    for (int i = t; i < zn; i += 64 * 256) z[i] = 0;
}

// ---------------------------------------------------------------------------
// K1: fused proj + pass-1 binning (R7 structure, verified).
// ---------------------------------------------------------------------------
template<bool XLBF>
__global__ __launch_bounds__(256) void proj_fill(
    const float* __restrict__ x, const __hip_bfloat16* __restrict__ wswz,
    const float* __restrict__ bl, const float* __restrict__ br,
    void* __restrict__ xl, __hip_bfloat16* __restrict__ xr,
    const int* __restrict__ ei, uint32_t* __restrict__ bcnt,
    char* __restrict__ region)
{
    __shared__ uint32_t s_sorted[E1];                 // 16 KB
    __shared__ uint32_t s_hist[NBUCK], s_lstart[NBUCK], s_loc[NBUCK], s_gbase[NBUCK];
    __shared__ uint32_t s_T;

    if (blockIdx.x >= FILLB) {
        proj_body<XLBF>((blockIdx.x - FILLB) * 16, threadIdx.x, x, wswz, bl, br, xl, xr);
        return;
    }

    int tid = threadIdx.x;
    int fb = blockIdx.x;
    for (int i = tid; i < NBUCK; i += 256) s_hist[i] = 0;
    __syncthreads();

    const uint32_t* eiw = (const uint32_t*)ei;
    bool zlo = (eiw[2 * (tid & 63) + 1] == 0u);
    bool is64 = __popcll(__ballot(zlo)) >= 32;
    int e0 = fb * E1;

    // pass A: histogram (LDS atomics only)
    for (int k = tid; k < E1; k += 256) {
        int e = e0 + k;
        int s = is64 ? (int)eiw[2 * (size_t)e] : ei[e];
        int t = is64 ? (int)eiw[2 * ((size_t)N_EDGES + e)] : ei[N_EDGES + e];
        if ((unsigned)s < N_NODES && (unsigned)t < N_NODES)
            atomicAdd(&s_hist[t >> 8], 1u);
    }
    __syncthreads();

    if (tid < NBUCK) s_gbase[tid] = atomicAdd(&bcnt[tid], s_hist[tid]);  // 196 global atomics
    if (tid == 0) {
        uint32_t acc = 0;
        for (int i = 0; i < NBUCK; ++i) { s_lstart[i] = acc; acc += s_hist[i]; }
        s_T = acc;
    }
    __syncthreads();
    if (tid < NBUCK) s_loc[tid] = s_lstart[tid];
    __syncthreads();

    // pass B: scatter into LDS, sorted by bucket (record = tgt<<16 | src)
    for (int k = tid; k < E1; k += 256) {
        int e = e0 + k;
        int s = is64 ? (int)eiw[2 * (size_t)e] : ei[e];
        int t = is64 ? (int)eiw[2 * ((size_t)N_EDGES + e)] : ei[N_EDGES + e];
        if ((unsigned)s < N_NODES && (unsigned)t < N_NODES) {
            uint32_t r = atomicAdd(&s_loc[t >> 8], 1u);
            s_sorted[r] = ((uint32_t)t << 16) | (uint32_t)s;
        }
    }
    __syncthreads();

    // pass C: stream out, per-bucket contiguous segments (coalesced)
    int T = (int)s_T;
    for (int k = tid; k < T; k += 256) {
        uint32_t v = s_sorted[k];
        uint32_t key = v >> 24;                        // tgt>>8
        uint32_t g = s_gbase[key] + (uint32_t)k - s_lstart[key];
        if (g < BCAP)
            ((uint32_t*)(region + (size_t)key * BSTRIDE))[g] = v;
    }
}

// ---------------------------------------------------------------------------
// K2: per-bucket CSR build (R7, verified).
// ---------------------------------------------------------------------------
__global__ __launch_bounds__(256) void csr_build(
    const uint32_t* __restrict__ bcnt, char* __restrict__ region,
    uint32_t* __restrict__ degs32)
{
    __shared__ uint16_t slab[256 * CAPR];   // 24576 B
    __shared__ uint32_t lcnt[256];
    int b = blockIdx.x, tid = threadIdx.x;
    lcnt[tid] = 0;
    __syncthreads();

    uint32_t* reg = (uint32_t*)(region + (size_t)b * BSTRIDE);
    int M = min((int)bcnt[b], BCAP);
    for (int k = tid; k < M; k += 256) {
        uint32_t v = reg[k];
        int node = (int)((v >> 16) & 255u);
        uint32_t pos = atomicAdd(&lcnt[node], 1u);
        if (pos < CAPR) slab[node * CAPR + pos] = (uint16_t)(v & 0xffffu);
    }
    __syncthreads();

    // slab -> global (overlay; all of reg was read before this barrier)
    const uint32_t* sw = (const uint32_t*)slab;
    for (int j = tid; j < (256 * CAPR / 2); j += 256) reg[j] = sw[j];
    if (tid < 64) {
        uint32_t p = 0;
#pragma unroll
        for (int q = 0; q < 4; ++q) {
            uint32_t d = min(lcnt[tid * 4 + q], (uint32_t)CAPR);
            p |= d << (q * 8);
        }
        degs32[b * 64 + tid] = p;
    }
}

// ---------------------------------------------------------------------------
// Legacy fill (R4): bucket-CSR via per-edge global atomics (fallback only).
// ---------------------------------------------------------------------------
__global__ __launch_bounds__(256) void fill_kernel(
    const int* __restrict__ ei, int cap,
    int* __restrict__ cnt, uint16_t* __restrict__ csr)
{
    const uint32_t* eiw = (const uint32_t*)ei;
    bool z = (eiw[2 * (threadIdx.x & 63) + 1] == 0u);
    bool is64 = __popcll(__ballot(z)) >= 32;

    int tid = blockIdx.x * 256 + threadIdx.x;
    int e0 = tid * E_PER;
    if (e0 >= N_EDGES) return;

    int src[E_PER], tgt[E_PER];
    if (is64) {
        const int4* ps = (const int4*)(eiw + 2 * (size_t)e0);
        const int4* pt = (const int4*)(eiw + 2 * ((size_t)N_EDGES + e0));
#pragma unroll
        for (int k = 0; k < 4; ++k) {
            int4 s = ps[k], t = pt[k];
            src[2 * k] = s.x; src[2 * k + 1] = s.z;
            tgt[2 * k] = t.x; tgt[2 * k + 1] = t.z;
        }
    } else {
        const int4* ps = (const int4*)(ei + e0);
        const int4* pt = (const int4*)(ei + N_EDGES + e0);
#pragma unroll
        for (int k = 0; k < 2; ++k) {
            int4 s = ps[k], t = pt[k];
            src[4 * k] = s.x; src[4 * k + 1] = s.y; src[4 * k + 2] = s.z; src[4 * k + 3] = s.w;
            tgt[4 * k] = t.x; tgt[4 * k + 1] = t.y; tgt[4 * k + 2] = t.z; tgt[4 * k + 3] = t.w;
        }
    }

    int pos[E_PER];
#pragma unroll
    for (int k = 0; k < E_PER; ++k) {
        bool ok = (unsigned)src[k] < N_NODES && (unsigned)tgt[k] < N_NODES;
        pos[k] = ok ? atomicAdd(&cnt[tgt[k]], 1) : cap;
    }
#pragma unroll
    for (int k = 0; k < E_PER; ++k)
        if (pos[k] < cap) csr[(size_t)tgt[k] * cap + pos[k]] = (uint16_t)src[k];
}

// Legacy standalone proj (xl = f32 into d_out).
__global__ __launch_bounds__(256) void proj_kernel(
    const float* __restrict__ x, const __hip_bfloat16* __restrict__ wswz,
    const float* __restrict__ bl, const float* __restrict__ br,
    float* __restrict__ xl, __hip_bfloat16* __restrict__ xr)
{
    proj_body<false>(blockIdx.x * 16, threadIdx.x, x, wswz, bl, br, xl, xr);
}

// ---------------------------------------------------------------------------
// Fused attention + aggregation (R8 re-laned layout, verified).
// R9: q read from bf16 xl (qbf=1, 128B/row) or f32 (legacy, from out);
//     neighbor registry pre-shifted to byte offsets (idx<<8 hoisted).
// ---------------------------------------------------------------------------
__global__ __launch_bounds__(256) void agg_kernel(
    const __hip_bfloat16* __restrict__ xr,
    const char* __restrict__ qb, int qbf,
    const char* __restrict__ degbase, int degpacked,
    const uint16_t* __restrict__ csr, int ldcsr, int cap,
    const float* __restrict__ att, const float* __restrict__ bias,
    float* out)
{
    int n = blockIdx.x * 4 + (threadIdx.x >> 6);
    if (n >= N_NODES) return;
    int lane = threadIdx.x & 63;
    int lpos = lane & 31;
    bool isB = lane >= 32;
    uint32_t voff = (uint32_t)lpos * 8u;

    const char* xrb = (const char*)xr;   // 256 B per node row

    f32x2 q01, q23;
    if (qbf) {
        uint2 qa = *(const uint2*)(qb + (size_t)n * 256 + voff);
        q01[0] = bf_lo(qa.x); q01[1] = bf_hi(qa.x);
        q23[0] = bf_lo(qa.y); q23[1] = bf_hi(qa.y);
    } else {
        f32x4 qv4 = *(const f32x4*)((const float*)qb + (size_t)n * IN_CH + lpos * 4);
        q01[0] = qv4[0]; q01[1] = qv4[1];
        q23[0] = qv4[2]; q23[1] = qv4[3];
    }
    f32x4 av4 = *(const f32x4*)(att + lpos * 4);
    f32x4 bv4 = *(const f32x4*)(bias + lpos * 4);
    const float L2E = 1.44269504088896f;      // exp2 prescale (exp(t)=exp2(t*log2e))
    f32x2 a01; a01[0] = av4[0] * L2E; a01[1] = av4[1] * L2E;
    f32x2 a23; a23[0] = av4[2] * L2E; a23[1] = av4[3] * L2E;

    int deg;
    if (degpacked) {
        uint32_t pk = ((const uint32_t*)degbase)[n >> 2];
        deg = (int)((pk >> ((n & 3) * 8)) & 255u);
    } else {
        deg = ((const int*)degbase)[n];
    }
    deg = min(deg, cap);
    deg = min(deg, 63);                  // items = deg+1 <= 64 (readlane bound)

    // item registry: lane k holds item k's row BYTE OFFSET (k=0 -> self)
    const uint16_t* lst = csr + (size_t)n * ldcsr;
    int idxreg = (int)lst[min(max(lane - 1, 0), cap - 1)];
    idxreg = (lane == 0) ? n : idxreg;
    idxreg <<= 8;                        // pre-shift: row byte offset (hoisted)

    int last = deg;                      // highest valid item index
    int FP   = (deg + 1) >> 1;           // full pairs
    int ODD  = (deg + 1) & 1;

    float lsum = 0.f;
    f32x2 acc0 = {0.f, 0.f}, acc1 = {0.f, 0.f};

#define PAIR_LOAD(p, udst) { \
        int sa_ = __builtin_amdgcn_readlane(idxreg, min(2 * (p), last)); \
        int sb_ = __builtin_amdgcn_readlane(idxreg, min(2 * (p) + 1, last)); \
        uint32_t vs_ = (uint32_t)(isB ? sb_ : sa_); \
        udst = *(const uint2*)(xrb + vs_ + voff); \
    }

#define PAIR_EVAL(u, MASKED) { \
        f32x2 c0_, c1_; \
        c0_[0] = bf_lo((u).x); c0_[1] = bf_hi((u).x); \
        c1_[0] = bf_lo((u).y); c1_[1] = bf_hi((u).y); \
        f32x2 r0_ = lrelu2(q01 + c0_) * a01; \
        f32x2 r1_ = lrelu2(q23 + c1_) * a23; \
        float t_ = (r0_[0] + r0_[1]) + (r1_[0] + r1_[1]); \
        t_ += DPPADD(t_, 0xB1);   /* quad_perm[1,0,3,2]: xor1 */ \
        t_ += DPPADD(t_, 0x4E);   /* quad_perm[2,3,0,1]: xor2 */ \
        t_ += DPPADD(t_, 0x141);  /* row_half_mirror: 8-lane sum done */ \
        float w_ = __builtin_amdgcn_exp2f(t_); \
        if (MASKED) w_ = isB ? 0.f : w_; \
        lsum += w_; \
        acc0 += w_ * c0_; \
        acc1 += w_ * c1_; \
    }

    // depth-2 pipeline over pairs (clamped indices -> extra loads are valid rows)
    uint2 u0, u1;
    PAIR_LOAD(0, u0);
    PAIR_LOAD(1, u1);
    for (int p = 0; p < FP; ++p) {
        uint2 u2;
        PAIR_LOAD(p + 2, u2);
        PAIR_EVAL(u0, false);
        u0 = u1; u1 = u2;
    }
    if (ODD) {
        PAIR_EVAL(u0, true);             // tail item: half B duplicates -> zeroed
    }

    // combine the two wave-halves (disjoint item sets, same channels)
    lsum    += __shfl_xor(lsum,    32);
    acc0[0] += __shfl_xor(acc0[0], 32);
    acc0[1] += __shfl_xor(acc0[1], 32);
    acc1[0] += __shfl_xor(acc1[0], 32);
    acc1[1] += __shfl_xor(acc1[1], 32);

    float inv = 1.f / lsum;
    if (lane < 32) {
        f32x4 ov;
        ov[0] = acc0[0] * inv + bv4[0];
        ov[1] = acc0[1] * inv + bv4[1];
        ov[2] = acc1[0] * inv + bv4[2];
        ov[3] = acc1[1] * inv + bv4[3];
        *(f32x4*)(out + (size_t)n * IN_CH + lpos * 4) = ov;
    }
#undef PAIR_LOAD
#undef PAIR_EVAL
}

extern "C" void kernel_launch(void* const* d_in, const int* in_sizes, int n_in,
                              void* d_out, int out_size, void* d_ws, size_t ws_size,
                              hipStream_t stream) {
    const float* x    = (const float*)d_in[0];
    const int*   ei   = (const int*)d_in[1];
    const float* Wl   = (const float*)d_in[2];
    const float* bl   = (const float*)d_in[3];
    const float* Wr   = (const float*)d_in[4];
    const float* br   = (const float*)d_in[5];
    const float* att  = (const float*)d_in[6];
    const float* bias = (const float*)d_in[7];
    float* out = (float*)d_out;

    // workspace layout (radix mode, bytes) — R9: xl stored bf16 in ws:
    //   xr     : [0, 12.8M)              bf16 [N, 128]
    //   xl     : [12.8M, 25.6M)          bf16 [N, 128]   (R9: was f32 in d_out)
    //   wswz   : [25.6M, +65536)         bf16 [4096*8]
    //   degs   : [25665536, +50176)      u8 packed degrees (196*64 u32)
    //   bcnt   : [25715712, +784)        u32 [196] (ends 25716496)
    //   region : [25716736, +196*24576)  bins overlaid with csr slabs
    char* ws = (char*)d_ws;
    __hip_bfloat16* xr = (__hip_bfloat16*)(ws);

    const size_t XL_OFF   = 12800000;
    const size_t WSWZ_OFF = 25600000;
    const size_t DEGS_OFF = 25665536;
    const size_t BCNT_OFF = 25715712;
    const size_t REG_OFF  = 25716736;    // >= BCNT_OFF+784 = 25716496, 512-aligned
    const size_t NEED     = REG_OFF + (size_t)NBUCK * BSTRIDE;   // 30,533,632

    if (ws_size >= NEED) {
        __hip_bfloat16* xl   = (__hip_bfloat16*)(ws + XL_OFF);
        __hip_bfloat16* wswz = (__hip_bfloat16*)(ws + WSWZ_OFF);
        uint32_t* degs   = (uint32_t*)(ws + DEGS_OFF);
        uint32_t* bcnt   = (uint32_t*)(ws + BCNT_OFF);
        char*     region = ws + REG_OFF;

        prep_kernel<<<64, 256, 0, stream>>>(Wl, Wr, wswz, (int*)bcnt, NBUCK);
        proj_fill<true><<<FILLB + N_NODES / 16, 256, 0, stream>>>(
            x, wswz, bl, br, (void*)xl, xr, ei, bcnt, region);
        csr_build<<<NBUCK, 256, 0, stream>>>(bcnt, region, degs);
        agg_kernel<<<N_NODES / 4, 256, 0, stream>>>(
            xr, (const char*)xl, 1, (const char*)degs, 1,
            (const uint16_t*)region, CAPR, CAPR, att, bias, out);
    } else {
        // legacy (R4) fallback: xl f32 in d_out, split-array CSR
        const size_t LG_WSWZ = 12800000;
        const size_t LG_CNT  = 12865536;
        const size_t CSR_BASE = 13065536;
        __hip_bfloat16* wswz = (__hip_bfloat16*)(ws + LG_WSWZ);
        int*      cnt = (int*)(ws + LG_CNT);
        uint16_t* csr = (uint16_t*)(ws + CSR_BASE);
        long long avail = (ws_size > CSR_BASE) ? (long long)(ws_size - CSR_BASE) : 0;
        int cap = (int)(avail / ((long long)N_NODES * 2));
        if (cap > 64) cap = 64;
        if (cap < 1)  cap = 1;

        prep_kernel<<<64, 256, 0, stream>>>(Wl, Wr, wswz, cnt, N_NODES);
        fill_kernel<<<FILL_BLOCKS, 256, 0, stream>>>(ei, cap, cnt, csr);
        proj_kernel<<<N_NODES / 16, 256, 0, stream>>>(x, wswz, bl, br, out, xr);
        agg_kernel<<<N_NODES / 4, 256, 0, stream>>>(
            xr, (const char*)out, 0, (const char*)cnt, 0,
            csr, cap, cap, att, bias, out);
    }
}

// Round 10
// 163.819 us; speedup vs baseline: 1.0014x; 1.0014x over previous
//
#include <hip/hip_runtime.h>
#include <hip/hip_bf16.h>
#include <stdint.h>

#define N_NODES 50000
#define N_EDGES 800000
#define IN_CH   128
#define NEG_SLOPE 0.2f

// ---- radix CSR build (R7 geometry, verified) ----
#define NBUCK   196              // bucket = tgt>>8 (256 nodes per bucket)
#define E1      4000             // edges per pass-1 block (16KB LDS, 8 blocks/CU)
#define FILLB   200              // 800000 / 4000
#define BCAP    6144             // u32 records per bucket region (24576/4)
#define BSTRIDE 24576            // bytes per bucket region == 256*48*2 (csr overlay)
#define CAPR    48               // csr slots per node (Poisson(16): P(deg>48)*N ~ 5e-11)
#define PROJ32B 1563             // ceil(50000/32) 32-row proj blocks (R10)

// ---- legacy fallback (R4) ----
#define E_PER 8
#define FILL_BLOCKS 391

typedef short short8 __attribute__((ext_vector_type(8)));
typedef float f32x4  __attribute__((ext_vector_type(4)));
typedef float f32x2  __attribute__((ext_vector_type(2)));

static __device__ __forceinline__ float bf_lo(uint32_t p) { return __uint_as_float(p << 16); }
static __device__ __forceinline__ float bf_hi(uint32_t p) { return __uint_as_float(p & 0xffff0000u); }
static __device__ __forceinline__ uint16_t f_to_bf(float f) {
    uint32_t u = __float_as_uint(f);
    u += 0x7fffu + ((u >> 16) & 1u);   // round-to-nearest-even
    return (uint16_t)(u >> 16);
}

// leaky-relu on a packed pair
static __device__ __forceinline__ f32x2 lrelu2(f32x2 x) {
    f32x2 s = x * NEG_SLOPE;
    f32x2 r;
    r[0] = fmaxf(x[0], s[0]);
    r[1] = fmaxf(x[1], s[1]);
    return r;
}

// single DPP add step (compiler handles hazards for the builtin form)
#define DPPADD(x, ctrl) __uint_as_float(__builtin_amdgcn_update_dpp(0, __float_as_uint(x), ctrl, 0xf, 0xf, true))

// ---------------------------------------------------------------------------
// Shared bodies
// ---------------------------------------------------------------------------
static __device__ __forceinline__ void wswz_body(
    int t, const float* __restrict__ Wl, const float* __restrict__ Wr,
    __hip_bfloat16* __restrict__ wswz)
{
    int ct = t >> 8, rem = t & 255;
    int ch = rem >> 6, lane = rem & 63;
    int m = lane & 15, quad = lane >> 4;
    const float* W = (ct < 8) ? Wl : Wr;
    int o = ((ct & 7) << 4) + m;
    const float* src = W + (size_t)o * IN_CH + ch * 32 + quad * 8;
    short8 f;
#pragma unroll
    for (int j = 0; j < 8; ++j) f[j] = (short)f_to_bf(src[j]);
    *(short8*)((short*)wswz + (size_t)t * 8) = f;
}

// legacy proj: 16 rows/block (fallback path only).
template<bool XLBF>
static __device__ __forceinline__ void proj_body(
    int rowbase, int tid,
    const float* __restrict__ x, const __hip_bfloat16* __restrict__ wswz,
    const float* __restrict__ bl, const float* __restrict__ br,
    void* __restrict__ xl, __hip_bfloat16* __restrict__ xr)
{
    int lane = tid & 63;
    int widx = tid >> 6;              // 0..3: ct group
    int m = lane & 15;
    int quad = lane >> 4;

    short8 afrag[4];
    const float* xrow = x + (size_t)(rowbase + m) * IN_CH;
#pragma unroll
    for (int ch = 0; ch < 4; ++ch) {
        f32x4 p0 = *(const f32x4*)(xrow + ch * 32 + quad * 8);
        f32x4 p1 = *(const f32x4*)(xrow + ch * 32 + quad * 8 + 4);
        short8 f;
#pragma unroll
        for (int j = 0; j < 4; ++j) { f[j] = (short)f_to_bf(p0[j]); f[j + 4] = (short)f_to_bf(p1[j]); }
        afrag[ch] = f;
    }

    const short* wz = (const short*)wswz;
    const float* bv = (widx < 2) ? bl : br;   // wave-uniform
#pragma unroll
    for (int cc = 0; cc < 4; ++cc) {
        int ct = widx * 4 + cc;
        int o = ((ct & 7) << 4) + m;
        f32x4 acc = {0.f, 0.f, 0.f, 0.f};
#pragma unroll
        for (int ch = 0; ch < 4; ++ch) {
            short8 bfrag = *(const short8*)(wz + ((size_t)(ct * 4 + ch) * 64 + lane) * 8);
            acc = __builtin_amdgcn_mfma_f32_16x16x32_bf16(afrag[ch], bfrag, acc, 0, 0, 0);
        }
        float bias_v = bv[o];
        // D layout: row = quad*4 + r, col = m   [m89-verified]
        if (widx < 2) {
#pragma unroll
            for (int r = 0; r < 4; ++r) {
                size_t idx = (size_t)(rowbase + quad * 4 + r) * IN_CH + o;
                if constexpr (XLBF)
                    ((__hip_bfloat16*)xl)[idx] = __float2bfloat16(acc[r] + bias_v);
                else
                    ((float*)xl)[idx] = acc[r] + bias_v;
            }
        } else {
#pragma unroll
            for (int r = 0; r < 4; ++r)
                xr[(size_t)(rowbase + quad * 4 + r) * IN_CH + o] = __float2bfloat16(acc[r] + bias_v);
        }
    }
}

// R10 proj: 32 rows/block — two A-tiles per wave share each B-fragment load.
// Halves wswz L2 traffic (200->100 MB total) and x re-reads; amortizes the
// per-wave prologue 2x.  Tail tile (rows >= N) guarded wave-uniformly.
static __device__ __forceinline__ void proj_body32(
    int rowbase, int tid,
    const float* __restrict__ x, const __hip_bfloat16* __restrict__ wswz,
    const float* __restrict__ bl, const float* __restrict__ br,
    __hip_bfloat16* __restrict__ xl, __hip_bfloat16* __restrict__ xr)
{
    int lane = tid & 63;
    int widx = tid >> 6;              // 0..3: ct group
    int m = lane & 15;
    int quad = lane >> 4;
    bool t1 = (rowbase + 16 < N_NODES);   // second tile valid (N%16==0: all-or-none)

    short8 af0[4], af1[4];
    const float* xrow0 = x + (size_t)(rowbase + m) * IN_CH;
#pragma unroll
    for (int ch = 0; ch < 4; ++ch) {
        f32x4 p0 = *(const f32x4*)(xrow0 + ch * 32 + quad * 8);
        f32x4 p1 = *(const f32x4*)(xrow0 + ch * 32 + quad * 8 + 4);
        short8 f;
#pragma unroll
        for (int j = 0; j < 4; ++j) { f[j] = (short)f_to_bf(p0[j]); f[j + 4] = (short)f_to_bf(p1[j]); }
        af0[ch] = f;
    }
    if (t1) {
        const float* xrow1 = x + (size_t)(rowbase + 16 + m) * IN_CH;
#pragma unroll
        for (int ch = 0; ch < 4; ++ch) {
            f32x4 p0 = *(const f32x4*)(xrow1 + ch * 32 + quad * 8);
            f32x4 p1 = *(const f32x4*)(xrow1 + ch * 32 + quad * 8 + 4);
            short8 f;
#pragma unroll
            for (int j = 0; j < 4; ++j) { f[j] = (short)f_to_bf(p0[j]); f[j + 4] = (short)f_to_bf(p1[j]); }
            af1[ch] = f;
        }
    }

    const short* wz = (const short*)wswz;
    const float* bv = (widx < 2) ? bl : br;   // wave-uniform
#pragma unroll
    for (int cc = 0; cc < 4; ++cc) {
        int ct = widx * 4 + cc;
        int o = ((ct & 7) << 4) + m;
        f32x4 acc0 = {0.f, 0.f, 0.f, 0.f};
        f32x4 acc1 = {0.f, 0.f, 0.f, 0.f};
#pragma unroll
        for (int ch = 0; ch < 4; ++ch) {
            short8 bfrag = *(const short8*)(wz + ((size_t)(ct * 4 + ch) * 64 + lane) * 8);
            acc0 = __builtin_amdgcn_mfma_f32_16x16x32_bf16(af0[ch], bfrag, acc0, 0, 0, 0);
            if (t1)
                acc1 = __builtin_amdgcn_mfma_f32_16x16x32_bf16(af1[ch], bfrag, acc1, 0, 0, 0);
        }
        float bias_v = bv[o];
        __hip_bfloat16* dst = (widx < 2) ? xl : xr;
        // D layout: row = quad*4 + r, col = m   [m89-verified]
#pragma unroll
        for (int r = 0; r < 4; ++r)
            dst[(size_t)(rowbase + quad * 4 + r) * IN_CH + o] = __float2bfloat16(acc0[r] + bias_v);
        if (t1) {
#pragma unroll
            for (int r = 0; r < 4; ++r)
                dst[(size_t)(rowbase + 16 + quad * 4 + r) * IN_CH + o] = __float2bfloat16(acc1[r] + bias_v);
        }
    }
}

// ---------------------------------------------------------------------------
// prep: wswz swizzle + zero zn ints at z (bucket counters OR legacy cnt).
// ---------------------------------------------------------------------------
__global__ __launch_bounds__(256) void prep_kernel(
    const float* __restrict__ Wl, const float* __restrict__ Wr,
    __hip_bfloat16* __restrict__ wswz, int* __restrict__ z, int zn)
{
    int t = blockIdx.x * 256 + threadIdx.x;
    if (t < 4096) wswz_body(t, Wl, Wr, wswz);
    for (int i = t; i < zn; i += 64 * 256) z[i] = 0;
}

// ---------------------------------------------------------------------------
// K1: fused proj + pass-1 binning (R7 fill structure; R10 32-row proj).
// ---------------------------------------------------------------------------
__global__ __launch_bounds__(256) void proj_fill(
    const float* __restrict__ x, const __hip_bfloat16* __restrict__ wswz,
    const float* __restrict__ bl, const float* __restrict__ br,
    __hip_bfloat16* __restrict__ xl, __hip_bfloat16* __restrict__ xr,
    const int* __restrict__ ei, uint32_t* __restrict__ bcnt,
    char* __restrict__ region)
{
    __shared__ uint32_t s_sorted[E1];                 // 16 KB
    __shared__ uint32_t s_hist[NBUCK], s_lstart[NBUCK], s_loc[NBUCK], s_gbase[NBUCK];
    __shared__ uint32_t s_T;

    if (blockIdx.x >= FILLB) {
        proj_body32((blockIdx.x - FILLB) * 32, threadIdx.x, x, wswz, bl, br, xl, xr);
        return;
    }

    int tid = threadIdx.x;
    int fb = blockIdx.x;
    for (int i = tid; i < NBUCK; i += 256) s_hist[i] = 0;
    __syncthreads();

    const uint32_t* eiw = (const uint32_t*)ei;
    bool zlo = (eiw[2 * (tid & 63) + 1] == 0u);
    bool is64 = __popcll(__ballot(zlo)) >= 32;
    int e0 = fb * E1;

    // pass A: histogram (LDS atomics only)
    for (int k = tid; k < E1; k += 256) {
        int e = e0 + k;
        int s = is64 ? (int)eiw[2 * (size_t)e] : ei[e];
        int t = is64 ? (int)eiw[2 * ((size_t)N_EDGES + e)] : ei[N_EDGES + e];
        if ((unsigned)s < N_NODES && (unsigned)t < N_NODES)
            atomicAdd(&s_hist[t >> 8], 1u);
    }
    __syncthreads();

    if (tid < NBUCK) s_gbase[tid] = atomicAdd(&bcnt[tid], s_hist[tid]);  // 196 global atomics
    if (tid == 0) {
        uint32_t acc = 0;
        for (int i = 0; i < NBUCK; ++i) { s_lstart[i] = acc; acc += s_hist[i]; }
        s_T = acc;
    }
    __syncthreads();
    if (tid < NBUCK) s_loc[tid] = s_lstart[tid];
    __syncthreads();

    // pass B: scatter into LDS, sorted by bucket (record = tgt<<16 | src)
    for (int k = tid; k < E1; k += 256) {
        int e = e0 + k;
        int s = is64 ? (int)eiw[2 * (size_t)e] : ei[e];
        int t = is64 ? (int)eiw[2 * ((size_t)N_EDGES + e)] : ei[N_EDGES + e];
        if ((unsigned)s < N_NODES && (unsigned)t < N_NODES) {
            uint32_t r = atomicAdd(&s_loc[t >> 8], 1u);
            s_sorted[r] = ((uint32_t)t << 16) | (uint32_t)s;
        }
    }
    __syncthreads();

    // pass C: stream out, per-bucket contiguous segments (coalesced)
    int T = (int)s_T;
    for (int k = tid; k < T; k += 256) {
        uint32_t v = s_sorted[k];
        uint32_t key = v >> 24;                        // tgt>>8
        uint32_t g = s_gbase[key] + (uint32_t)k - s_lstart[key];
        if (g < BCAP)
            ((uint32_t*)(region + (size_t)key * BSTRIDE))[g] = v;
    }
}

// ---------------------------------------------------------------------------
// K2: per-bucket CSR build (R7, verified).
// ---------------------------------------------------------------------------
__global__ __launch_bounds__(256) void csr_build(
    const uint32_t* __restrict__ bcnt, char* __restrict__ region,
    uint32_t* __restrict__ degs32)
{
    __shared__ uint16_t slab[256 * CAPR];   // 24576 B
    __shared__ uint32_t lcnt[256];
    int b = blockIdx.x, tid = threadIdx.x;
    lcnt[tid] = 0;
    __syncthreads();

    uint32_t* reg = (uint32_t*)(region + (size_t)b * BSTRIDE);
    int M = min((int)bcnt[b], BCAP);
    for (int k = tid; k < M; k += 256) {
        uint32_t v = reg[k];
        int node = (int)((v >> 16) & 255u);
        uint32_t pos = atomicAdd(&lcnt[node], 1u);
        if (pos < CAPR) slab[node * CAPR + pos] = (uint16_t)(v & 0xffffu);
    }
    __syncthreads();

    // slab -> global (overlay; all of reg was read before this barrier)
    const uint32_t* sw = (const uint32_t*)slab;
    for (int j = tid; j < (256 * CAPR / 2); j += 256) reg[j] = sw[j];
    if (tid < 64) {
        uint32_t p = 0;
#pragma unroll
        for (int q = 0; q < 4; ++q) {
            uint32_t d = min(lcnt[tid * 4 + q], (uint32_t)CAPR);
            p |= d << (q * 8);
        }
        degs32[b * 64 + tid] = p;
    }
}

// ---------------------------------------------------------------------------
// Legacy fill (R4): bucket-CSR via per-edge global atomics (fallback only).
// ---------------------------------------------------------------------------
__global__ __launch_bounds__(256) void fill_kernel(
    const int* __restrict__ ei, int cap,
    int* __restrict__ cnt, uint16_t* __restrict__ csr)
{
    const uint32_t* eiw = (const uint32_t*)ei;
    bool z = (eiw[2 * (threadIdx.x & 63) + 1] == 0u);
    bool is64 = __popcll(__ballot(z)) >= 32;

    int tid = blockIdx.x * 256 + threadIdx.x;
    int e0 = tid * E_PER;
    if (e0 >= N_EDGES) return;

    int src[E_PER], tgt[E_PER];
    if (is64) {
        const int4* ps = (const int4*)(eiw + 2 * (size_t)e0);
        const int4* pt = (const int4*)(eiw + 2 * ((size_t)N_EDGES + e0));
#pragma unroll
        for (int k = 0; k < 4; ++k) {
            int4 s = ps[k], t = pt[k];
            src[2 * k] = s.x; src[2 * k + 1] = s.z;
            tgt[2 * k] = t.x; tgt[2 * k + 1] = t.z;
        }
    } else {
        const int4* ps = (const int4*)(ei + e0);
        const int4* pt = (const int4*)(ei + N_EDGES + e0);
#pragma unroll
        for (int k = 0; k < 2; ++k) {
            int4 s = ps[k], t = pt[k];
            src[4 * k] = s.x; src[4 * k + 1] = s.y; src[4 * k + 2] = s.z; src[4 * k + 3] = s.w;
            tgt[4 * k] = t.x; tgt[4 * k + 1] = t.y; tgt[4 * k + 2] = t.z; tgt[4 * k + 3] = t.w;
        }
    }

    int pos[E_PER];
#pragma unroll
    for (int k = 0; k < E_PER; ++k) {
        bool ok = (unsigned)src[k] < N_NODES && (unsigned)tgt[k] < N_NODES;
        pos[k] = ok ? atomicAdd(&cnt[tgt[k]], 1) : cap;
    }
#pragma unroll
    for (int k = 0; k < E_PER; ++k)
        if (pos[k] < cap) csr[(size_t)tgt[k] * cap + pos[k]] = (uint16_t)src[k];
}

// Legacy standalone proj (xl = f32 into d_out).
__global__ __launch_bounds__(256) void proj_kernel(
    const float* __restrict__ x, const __hip_bfloat16* __restrict__ wswz,
    const float* __restrict__ bl, const float* __restrict__ br,
    float* __restrict__ xl, __hip_bfloat16* __restrict__ xr)
{
    proj_body<false>(blockIdx.x * 16, threadIdx.x, x, wswz, bl, br, xl, xr);
}

// ---------------------------------------------------------------------------
// Fused attention + aggregation (R8 re-laned layout; R10: depth-3 pipeline).
// ---------------------------------------------------------------------------
__global__ __launch_bounds__(256) void agg_kernel(
    const __hip_bfloat16* __restrict__ xr,
    const char* __restrict__ qb, int qbf,
    const char* __restrict__ degbase, int degpacked,
    const uint16_t* __restrict__ csr, int ldcsr, int cap,
    const float* __restrict__ att, const float* __restrict__ bias,
    float* out)
{
    int n = blockIdx.x * 4 + (threadIdx.x >> 6);
    if (n >= N_NODES) return;
    int lane = threadIdx.x & 63;
    int lpos = lane & 31;
    bool isB = lane >= 32;
    uint32_t voff = (uint32_t)lpos * 8u;

    const char* xrb = (const char*)xr;   // 256 B per node row

    f32x2 q01, q23;
    if (qbf) {
        uint2 qa = *(const uint2*)(qb + (size_t)n * 256 + voff);
        q01[0] = bf_lo(qa.x); q01[1] = bf_hi(qa.x);
        q23[0] = bf_lo(qa.y); q23[1] = bf_hi(qa.y);
    } else {
        f32x4 qv4 = *(const f32x4*)((const float*)qb + (size_t)n * IN_CH + lpos * 4);
        q01[0] = qv4[0]; q01[1] = qv4[1];
        q23[0] = qv4[2]; q23[1] = qv4[3];
    }
    f32x4 av4 = *(const f32x4*)(att + lpos * 4);
    f32x4 bv4 = *(const f32x4*)(bias + lpos * 4);
    const float L2E = 1.44269504088896f;      // exp2 prescale (exp(t)=exp2(t*log2e))
    f32x2 a01; a01[0] = av4[0] * L2E; a01[1] = av4[1] * L2E;
    f32x2 a23; a23[0] = av4[2] * L2E; a23[1] = av4[3] * L2E;

    int deg;
    if (degpacked) {
        uint32_t pk = ((const uint32_t*)degbase)[n >> 2];
        deg = (int)((pk >> ((n & 3) * 8)) & 255u);
    } else {
        deg = ((const int*)degbase)[n];
    }
    deg = min(deg, cap);
    deg = min(deg, 63);                  // items = deg+1 <= 64 (readlane bound)

    // item registry: lane k holds item k's row BYTE OFFSET (k=0 -> self)
    const uint16_t* lst = csr + (size_t)n * ldcsr;
    int idxreg = (int)lst[min(max(lane - 1, 0), cap - 1)];
    idxreg = (lane == 0) ? n : idxreg;
    idxreg <<= 8;                        // pre-shift: row byte offset (hoisted)

    int last = deg;                      // highest valid item index
    int FP   = (deg + 1) >> 1;           // full pairs
    int ODD  = (deg + 1) & 1;

    float lsum = 0.f;
    f32x2 acc0 = {0.f, 0.f}, acc1 = {0.f, 0.f};

#define PAIR_LOAD(p, udst) { \
        int sa_ = __builtin_amdgcn_readlane(idxreg, min(2 * (p), last)); \
        int sb_ = __builtin_amdgcn_readlane(idxreg, min(2 * (p) + 1, last)); \
        uint32_t vs_ = (uint32_t)(isB ? sb_ : sa_); \
        udst = *(const uint2*)(xrb + vs_ + voff); \
    }

#define PAIR_EVAL(u, MASKED) { \
        f32x2 c0_, c1_; \
        c0_[0] = bf_lo((u).x); c0_[1] = bf_hi((u).x); \
        c1_[0] = bf_lo((u).y); c1_[1] = bf_hi((u).y); \
        f32x2 r0_ = lrelu2(q01 + c0_) * a01; \
        f32x2 r1_ = lrelu2(q23 + c1_) * a23; \
        float t_ = (r0_[0] + r0_[1]) + (r1_[0] + r1_[1]); \
        t_ += DPPADD(t_, 0xB1);   /* quad_perm[1,0,3,2]: xor1 */ \
        t_ += DPPADD(t_, 0x4E);   /* quad_perm[2,3,0,1]: xor2 */ \
        t_ += DPPADD(t_, 0x141);  /* row_half_mirror: 8-lane sum done */ \
        float w_ = __builtin_amdgcn_exp2f(t_); \
        if (MASKED) w_ = isB ? 0.f : w_; \
        lsum += w_; \
        acc0 += w_ * c0_; \
        acc1 += w_ * c1_; \
    }

    // depth-3 pipeline over pairs (clamped indices -> extra loads are valid rows)
    uint2 u0, u1, u2;
    PAIR_LOAD(0, u0);
    PAIR_LOAD(1, u1);
    PAIR_LOAD(2, u2);
    for (int p = 0; p < FP; ++p) {
        uint2 u3;
        PAIR_LOAD(p + 3, u3);
        PAIR_EVAL(u0, false);
        u0 = u1; u1 = u2; u2 = u3;
    }
    if (ODD) {
        PAIR_EVAL(u0, true);             // tail item: half B duplicates -> zeroed
    }

    // combine the two wave-halves (disjoint item sets, same channels)
    lsum    += __shfl_xor(lsum,    32);
    acc0[0] += __shfl_xor(acc0[0], 32);
    acc0[1] += __shfl_xor(acc0[1], 32);
    acc1[0] += __shfl_xor(acc1[0], 32);
    acc1[1] += __shfl_xor(acc1[1], 32);

    float inv = 1.f / lsum;
    if (lane < 32) {
        f32x4 ov;
        ov[0] = acc0[0] * inv + bv4[0];
        ov[1] = acc0[1] * inv + bv4[1];
        ov[2] = acc1[0] * inv + bv4[2];
        ov[3] = acc1[1] * inv + bv4[3];
        *(f32x4*)(out + (size_t)n * IN_CH + lpos * 4) = ov;
    }
#undef PAIR_LOAD
#undef PAIR_EVAL
}

extern "C" void kernel_launch(void* const* d_in, const int* in_sizes, int n_in,
                              void* d_out, int out_size, void* d_ws, size_t ws_size,
                              hipStream_t stream) {
    const float* x    = (const float*)d_in[0];
    const int*   ei   = (const int*)d_in[1];
    const float* Wl   = (const float*)d_in[2];
    const float* bl   = (const float*)d_in[3];
    const float* Wr   = (const float*)d_in[4];
    const float* br   = (const float*)d_in[5];
    const float* att  = (const float*)d_in[6];
    const float* bias = (const float*)d_in[7];
    float* out = (float*)d_out;

    // workspace layout (radix mode, bytes):
    //   xr     : [0, 12.8M)              bf16 [N, 128]
    //   xl     : [12.8M, 25.6M)          bf16 [N, 128]
    //   wswz   : [25.6M, +65536)         bf16 [4096*8]
    //   degs   : [25665536, +50176)      u8 packed degrees (196*64 u32)
    //   bcnt   : [25715712, +784)        u32 [196] (ends 25716496)
    //   region : [25716736, +196*24576)  bins overlaid with csr slabs
    char* ws = (char*)d_ws;
    __hip_bfloat16* xr = (__hip_bfloat16*)(ws);

    const size_t XL_OFF   = 12800000;
    const size_t WSWZ_OFF = 25600000;
    const size_t DEGS_OFF = 25665536;
    const size_t BCNT_OFF = 25715712;
    const size_t REG_OFF  = 25716736;    // >= BCNT_OFF+784 = 25716496, 512-aligned
    const size_t NEED     = REG_OFF + (size_t)NBUCK * BSTRIDE;   // 30,533,632

    if (ws_size >= NEED) {
        __hip_bfloat16* xl   = (__hip_bfloat16*)(ws + XL_OFF);
        __hip_bfloat16* wswz = (__hip_bfloat16*)(ws + WSWZ_OFF);
        uint32_t* degs   = (uint32_t*)(ws + DEGS_OFF);
        uint32_t* bcnt   = (uint32_t*)(ws + BCNT_OFF);
        char*     region = ws + REG_OFF;

        prep_kernel<<<64, 256, 0, stream>>>(Wl, Wr, wswz, (int*)bcnt, NBUCK);
        proj_fill<<<FILLB + PROJ32B, 256, 0, stream>>>(
            x, wswz, bl, br, xl, xr, ei, bcnt, region);
        csr_build<<<NBUCK, 256, 0, stream>>>(bcnt, region, degs);
        agg_kernel<<<N_NODES / 4, 256, 0, stream>>>(
            xr, (const char*)xl, 1, (const char*)degs, 1,
            (const uint16_t*)region, CAPR, CAPR, att, bias, out);
    } else {
        // legacy (R4) fallback: xl f32 in d_out, split-array CSR
        const size_t LG_WSWZ = 12800000;
        const size_t LG_CNT  = 12865536;
        const size_t CSR_BASE = 13065536;
        __hip_bfloat16* wswz = (__hip_bfloat16*)(ws + LG_WSWZ);
        int*      cnt = (int*)(ws + LG_CNT);
        uint16_t* csr = (uint16_t*)(ws + CSR_BASE);
        long long avail = (ws_size > CSR_BASE) ? (long long)(ws_size - CSR_BASE) : 0;
        int cap = (int)(avail / ((long long)N_NODES * 2));
        if (cap > 64) cap = 64;
        if (cap < 1)  cap = 1;

        prep_kernel<<<64, 256, 0, stream>>>(Wl, Wr, wswz, cnt, N_NODES);
        fill_kernel<<<FILL_BLOCKS, 256, 0, stream>>>(ei, cap, cnt, csr);
        proj_kernel<<<N_NODES / 16, 256, 0, stream>>>(x, wswz, bl, br, out, xr);
        agg_kernel<<<N_NODES / 4, 256, 0, stream>>>(
            xr, (const char*)out, 0, (const char*)cnt, 0,
            csr, cap, cap, att, bias, out);
    }
}

// Round 11
// 161.634 us; speedup vs baseline: 1.0149x; 1.0135x over previous
//
#include <hip/hip_runtime.h>
#include <hip/hip_bf16.h>
#include <stdint.h>

#define N_NODES 50000
#define N_EDGES 800000
#define IN_CH   128
#define NEG_SLOPE 0.2f

// ---- radix CSR build (R7 geometry, verified) ----
#define NBUCK   196              // bucket = tgt>>8 (256 nodes per bucket)
#define E1      4000             // edges per pass-1 block (16KB LDS, 8 blocks/CU)
#define FILLB   200              // 800000 / 4000
#define BCAP    6144             // u32 records per bucket region (24576/4)
#define BSTRIDE 24576            // bytes per bucket region == 256*48*2 (csr overlay)
#define CAPR    48               // csr slots per node (Poisson(16): P(deg>48)*N ~ 5e-11)
#define PROJ32B 1563             // ceil(50000/32) 32-row proj blocks

// ---- legacy fallback (R4) ----
#define E_PER 8
#define FILL_BLOCKS 391

typedef short short8 __attribute__((ext_vector_type(8)));
typedef float f32x4  __attribute__((ext_vector_type(4)));
typedef float f32x2  __attribute__((ext_vector_type(2)));
typedef _Float16 h2  __attribute__((ext_vector_type(2)));

static __device__ __forceinline__ float bf_lo(uint32_t p) { return __uint_as_float(p << 16); }
static __device__ __forceinline__ float bf_hi(uint32_t p) { return __uint_as_float(p & 0xffff0000u); }
static __device__ __forceinline__ uint16_t f_to_bf(float f) {
    uint32_t u = __float_as_uint(f);
    u += 0x7fffu + ((u >> 16) & 1u);   // round-to-nearest-even
    return (uint16_t)(u >> 16);
}

// leaky-relu on a packed f32 pair (legacy agg path)
static __device__ __forceinline__ f32x2 lrelu2(f32x2 x) {
    f32x2 s = x * NEG_SLOPE;
    f32x2 r;
    r[0] = fmaxf(x[0], s[0]);
    r[1] = fmaxf(x[1], s[1]);
    return r;
}

// packed f16 max -> v_pk_max_f16
static __device__ __forceinline__ h2 h2max(h2 a, h2 b) {
#if __has_builtin(__builtin_elementwise_max)
    return __builtin_elementwise_max(a, b);
#else
    h2 r; r[0] = a[0] > b[0] ? a[0] : b[0]; r[1] = a[1] > b[1] ? a[1] : b[1]; return r;
#endif
}
// v_dot2_f32_f16: c + a[0]*b[0] + a[1]*b[1] (f32 accumulate)
static __device__ __forceinline__ float fdot2h(h2 a, h2 b, float c) {
#if __has_builtin(__builtin_amdgcn_fdot2)
    return __builtin_amdgcn_fdot2(a, b, c, false);
#else
    return c + (float)a[0] * (float)b[0] + (float)a[1] * (float)b[1];
#endif
}

// single DPP add step (compiler handles hazards for the builtin form)
#define DPPADD(x, ctrl) __uint_as_float(__builtin_amdgcn_update_dpp(0, __float_as_uint(x), ctrl, 0xf, 0xf, true))

// ---------------------------------------------------------------------------
// Shared bodies
// ---------------------------------------------------------------------------
static __device__ __forceinline__ void wswz_body(
    int t, const float* __restrict__ Wl, const float* __restrict__ Wr,
    __hip_bfloat16* __restrict__ wswz)
{
    int ct = t >> 8, rem = t & 255;
    int ch = rem >> 6, lane = rem & 63;
    int m = lane & 15, quad = lane >> 4;
    const float* W = (ct < 8) ? Wl : Wr;
    int o = ((ct & 7) << 4) + m;
    const float* src = W + (size_t)o * IN_CH + ch * 32 + quad * 8;
    short8 f;
#pragma unroll
    for (int j = 0; j < 8; ++j) f[j] = (short)f_to_bf(src[j]);
    *(short8*)((short*)wswz + (size_t)t * 8) = f;
}

// legacy proj: 16 rows/block (fallback path only; xl f32, xr bf16).
static __device__ __forceinline__ void proj_body16(
    int rowbase, int tid,
    const float* __restrict__ x, const __hip_bfloat16* __restrict__ wswz,
    const float* __restrict__ bl, const float* __restrict__ br,
    float* __restrict__ xl, __hip_bfloat16* __restrict__ xr)
{
    int lane = tid & 63;
    int widx = tid >> 6;              // 0..3: ct group
    int m = lane & 15;
    int quad = lane >> 4;

    short8 afrag[4];
    const float* xrow = x + (size_t)(rowbase + m) * IN_CH;
#pragma unroll
    for (int ch = 0; ch < 4; ++ch) {
        f32x4 p0 = *(const f32x4*)(xrow + ch * 32 + quad * 8);
        f32x4 p1 = *(const f32x4*)(xrow + ch * 32 + quad * 8 + 4);
        short8 f;
#pragma unroll
        for (int j = 0; j < 4; ++j) { f[j] = (short)f_to_bf(p0[j]); f[j + 4] = (short)f_to_bf(p1[j]); }
        afrag[ch] = f;
    }

    const short* wz = (const short*)wswz;
    const float* bv = (widx < 2) ? bl : br;   // wave-uniform
#pragma unroll
    for (int cc = 0; cc < 4; ++cc) {
        int ct = widx * 4 + cc;
        int o = ((ct & 7) << 4) + m;
        f32x4 acc = {0.f, 0.f, 0.f, 0.f};
#pragma unroll
        for (int ch = 0; ch < 4; ++ch) {
            short8 bfrag = *(const short8*)(wz + ((size_t)(ct * 4 + ch) * 64 + lane) * 8);
            acc = __builtin_amdgcn_mfma_f32_16x16x32_bf16(afrag[ch], bfrag, acc, 0, 0, 0);
        }
        float bias_v = bv[o];
        // D layout: row = quad*4 + r, col = m   [m89-verified]
        if (widx < 2) {
#pragma unroll
            for (int r = 0; r < 4; ++r)
                xl[(size_t)(rowbase + quad * 4 + r) * IN_CH + o] = acc[r] + bias_v;
        } else {
#pragma unroll
            for (int r = 0; r < 4; ++r)
                xr[(size_t)(rowbase + quad * 4 + r) * IN_CH + o] = __float2bfloat16(acc[r] + bias_v);
        }
    }
}

// R10/R11 proj: 32 rows/block, two A-tiles share each B-fragment; R11: f16 out.
static __device__ __forceinline__ void proj_body32(
    int rowbase, int tid,
    const float* __restrict__ x, const __hip_bfloat16* __restrict__ wswz,
    const float* __restrict__ bl, const float* __restrict__ br,
    _Float16* __restrict__ xl, _Float16* __restrict__ xr)
{
    int lane = tid & 63;
    int widx = tid >> 6;              // 0..3: ct group
    int m = lane & 15;
    int quad = lane >> 4;
    bool t1 = (rowbase + 16 < N_NODES);   // second tile valid

    short8 af0[4], af1[4];
    const float* xrow0 = x + (size_t)(rowbase + m) * IN_CH;
#pragma unroll
    for (int ch = 0; ch < 4; ++ch) {
        f32x4 p0 = *(const f32x4*)(xrow0 + ch * 32 + quad * 8);
        f32x4 p1 = *(const f32x4*)(xrow0 + ch * 32 + quad * 8 + 4);
        short8 f;
#pragma unroll
        for (int j = 0; j < 4; ++j) { f[j] = (short)f_to_bf(p0[j]); f[j + 4] = (short)f_to_bf(p1[j]); }
        af0[ch] = f;
    }
    if (t1) {
        const float* xrow1 = x + (size_t)(rowbase + 16 + m) * IN_CH;
#pragma unroll
        for (int ch = 0; ch < 4; ++ch) {
            f32x4 p0 = *(const f32x4*)(xrow1 + ch * 32 + quad * 8);
            f32x4 p1 = *(const f32x4*)(xrow1 + ch * 32 + quad * 8 + 4);
            short8 f;
#pragma unroll
            for (int j = 0; j < 4; ++j) { f[j] = (short)f_to_bf(p0[j]); f[j + 4] = (short)f_to_bf(p1[j]); }
            af1[ch] = f;
        }
    }

    const short* wz = (const short*)wswz;
    const float* bv = (widx < 2) ? bl : br;   // wave-uniform
#pragma unroll
    for (int cc = 0; cc < 4; ++cc) {
        int ct = widx * 4 + cc;
        int o = ((ct & 7) << 4) + m;
        f32x4 acc0 = {0.f, 0.f, 0.f, 0.f};
        f32x4 acc1 = {0.f, 0.f, 0.f, 0.f};
#pragma unroll
        for (int ch = 0; ch < 4; ++ch) {
            short8 bfrag = *(const short8*)(wz + ((size_t)(ct * 4 + ch) * 64 + lane) * 8);
            acc0 = __builtin_amdgcn_mfma_f32_16x16x32_bf16(af0[ch], bfrag, acc0, 0, 0, 0);
            if (t1)
                acc1 = __builtin_amdgcn_mfma_f32_16x16x32_bf16(af1[ch], bfrag, acc1, 0, 0, 0);
        }
        float bias_v = bv[o];
        _Float16* dst = (widx < 2) ? xl : xr;
        // D layout: row = quad*4 + r, col = m   [m89-verified]
#pragma unroll
        for (int r = 0; r < 4; ++r)
            dst[(size_t)(rowbase + quad * 4 + r) * IN_CH + o] = (_Float16)(acc0[r] + bias_v);
        if (t1) {
#pragma unroll
            for (int r = 0; r < 4; ++r)
                dst[(size_t)(rowbase + 16 + quad * 4 + r) * IN_CH + o] = (_Float16)(acc1[r] + bias_v);
        }
    }
}

// ---------------------------------------------------------------------------
// prep: wswz swizzle + zero zn ints at z (bucket counters OR legacy cnt).
// ---------------------------------------------------------------------------
__global__ __launch_bounds__(256) void prep_kernel(
    const float* __restrict__ Wl, const float* __restrict__ Wr,
    __hip_bfloat16* __restrict__ wswz, int* __restrict__ z, int zn)
{
    int t = blockIdx.x * 256 + threadIdx.x;
    if (t < 4096) wswz_body(t, Wl, Wr, wswz);
    for (int i = t; i < zn; i += 64 * 256) z[i] = 0;
}

// ---------------------------------------------------------------------------
// K1: fused proj + pass-1 binning (R7 fill structure; 32-row f16 proj).
// ---------------------------------------------------------------------------
__global__ __launch_bounds__(256) void proj_fill(
    const float* __restrict__ x, const __hip_bfloat16* __restrict__ wswz,
    const float* __restrict__ bl, const float* __restrict__ br,
    _Float16* __restrict__ xl, _Float16* __restrict__ xr,
    const int* __restrict__ ei, uint32_t* __restrict__ bcnt,
    char* __restrict__ region)
{
    __shared__ uint32_t s_sorted[E1];                 // 16 KB
    __shared__ uint32_t s_hist[NBUCK], s_lstart[NBUCK], s_loc[NBUCK], s_gbase[NBUCK];
    __shared__ uint32_t s_T;

    if (blockIdx.x >= FILLB) {
        proj_body32((blockIdx.x - FILLB) * 32, threadIdx.x, x, wswz, bl, br, xl, xr);
        return;
    }

    int tid = threadIdx.x;
    int fb = blockIdx.x;
    for (int i = tid; i < NBUCK; i += 256) s_hist[i] = 0;
    __syncthreads();

    const uint32_t* eiw = (const uint32_t*)ei;
    bool zlo = (eiw[2 * (tid & 63) + 1] == 0u);
    bool is64 = __popcll(__ballot(zlo)) >= 32;
    int e0 = fb * E1;

    // pass A: histogram (LDS atomics only)
    for (int k = tid; k < E1; k += 256) {
        int e = e0 + k;
        int s = is64 ? (int)eiw[2 * (size_t)e] : ei[e];
        int t = is64 ? (int)eiw[2 * ((size_t)N_EDGES + e)] : ei[N_EDGES + e];
        if ((unsigned)s < N_NODES && (unsigned)t < N_NODES)
            atomicAdd(&s_hist[t >> 8], 1u);
    }
    __syncthreads();

    if (tid < NBUCK) s_gbase[tid] = atomicAdd(&bcnt[tid], s_hist[tid]);  // 196 global atomics
    if (tid == 0) {
        uint32_t acc = 0;
        for (int i = 0; i < NBUCK; ++i) { s_lstart[i] = acc; acc += s_hist[i]; }
        s_T = acc;
    }
    __syncthreads();
    if (tid < NBUCK) s_loc[tid] = s_lstart[tid];
    __syncthreads();

    // pass B: scatter into LDS, sorted by bucket (record = tgt<<16 | src)
    for (int k = tid; k < E1; k += 256) {
        int e = e0 + k;
        int s = is64 ? (int)eiw[2 * (size_t)e] : ei[e];
        int t = is64 ? (int)eiw[2 * ((size_t)N_EDGES + e)] : ei[N_EDGES + e];
        if ((unsigned)s < N_NODES && (unsigned)t < N_NODES) {
            uint32_t r = atomicAdd(&s_loc[t >> 8], 1u);
            s_sorted[r] = ((uint32_t)t << 16) | (uint32_t)s;
        }
    }
    __syncthreads();

    // pass C: stream out, per-bucket contiguous segments (coalesced)
    int T = (int)s_T;
    for (int k = tid; k < T; k += 256) {
        uint32_t v = s_sorted[k];
        uint32_t key = v >> 24;                        // tgt>>8
        uint32_t g = s_gbase[key] + (uint32_t)k - s_lstart[key];
        if (g < BCAP)
            ((uint32_t*)(region + (size_t)key * BSTRIDE))[g] = v;
    }
}

// ---------------------------------------------------------------------------
// K2: per-bucket CSR build (R7, verified).
// ---------------------------------------------------------------------------
__global__ __launch_bounds__(256) void csr_build(
    const uint32_t* __restrict__ bcnt, char* __restrict__ region,
    uint32_t* __restrict__ degs32)
{
    __shared__ uint16_t slab[256 * CAPR];   // 24576 B
    __shared__ uint32_t lcnt[256];
    int b = blockIdx.x, tid = threadIdx.x;
    lcnt[tid] = 0;
    __syncthreads();

    uint32_t* reg = (uint32_t*)(region + (size_t)b * BSTRIDE);
    int M = min((int)bcnt[b], BCAP);
    for (int k = tid; k < M; k += 256) {
        uint32_t v = reg[k];
        int node = (int)((v >> 16) & 255u);
        uint32_t pos = atomicAdd(&lcnt[node], 1u);
        if (pos < CAPR) slab[node * CAPR + pos] = (uint16_t)(v & 0xffffu);
    }
    __syncthreads();

    // slab -> global (overlay; all of reg was read before this barrier)
    const uint32_t* sw = (const uint32_t*)slab;
    for (int j = tid; j < (256 * CAPR / 2); j += 256) reg[j] = sw[j];
    if (tid < 64) {
        uint32_t p = 0;
#pragma unroll
        for (int q = 0; q < 4; ++q) {
            uint32_t d = min(lcnt[tid * 4 + q], (uint32_t)CAPR);
            p |= d << (q * 8);
        }
        degs32[b * 64 + tid] = p;
    }
}

// ---------------------------------------------------------------------------
// Legacy fill (R4): bucket-CSR via per-edge global atomics (fallback only).
// ---------------------------------------------------------------------------
__global__ __launch_bounds__(256) void fill_kernel(
    const int* __restrict__ ei, int cap,
    int* __restrict__ cnt, uint16_t* __restrict__ csr)
{
    const uint32_t* eiw = (const uint32_t*)ei;
    bool z = (eiw[2 * (threadIdx.x & 63) + 1] == 0u);
    bool is64 = __popcll(__ballot(z)) >= 32;

    int tid = blockIdx.x * 256 + threadIdx.x;
    int e0 = tid * E_PER;
    if (e0 >= N_EDGES) return;

    int src[E_PER], tgt[E_PER];
    if (is64) {
        const int4* ps = (const int4*)(eiw + 2 * (size_t)e0);
        const int4* pt = (const int4*)(eiw + 2 * ((size_t)N_EDGES + e0));
#pragma unroll
        for (int k = 0; k < 4; ++k) {
            int4 s = ps[k], t = pt[k];
            src[2 * k] = s.x; src[2 * k + 1] = s.z;
            tgt[2 * k] = t.x; tgt[2 * k + 1] = t.z;
        }
    } else {
        const int4* ps = (const int4*)(ei + e0);
        const int4* pt = (const int4*)(ei + N_EDGES + e0);
#pragma unroll
        for (int k = 0; k < 2; ++k) {
            int4 s = ps[k], t = pt[k];
            src[4 * k] = s.x; src[4 * k + 1] = s.y; src[4 * k + 2] = s.z; src[4 * k + 3] = s.w;
            tgt[4 * k] = t.x; tgt[4 * k + 1] = t.y; tgt[4 * k + 2] = t.z; tgt[4 * k + 3] = t.w;
        }
    }

    int pos[E_PER];
#pragma unroll
    for (int k = 0; k < E_PER; ++k) {
        bool ok = (unsigned)src[k] < N_NODES && (unsigned)tgt[k] < N_NODES;
        pos[k] = ok ? atomicAdd(&cnt[tgt[k]], 1) : cap;
    }
#pragma unroll
    for (int k = 0; k < E_PER; ++k)
        if (pos[k] < cap) csr[(size_t)tgt[k] * cap + pos[k]] = (uint16_t)src[k];
}

// Legacy standalone proj (xl = f32 into d_out, xr = bf16).
__global__ __launch_bounds__(256) void proj_kernel(
    const float* __restrict__ x, const __hip_bfloat16* __restrict__ wswz,
    const float* __restrict__ bl, const float* __restrict__ br,
    float* __restrict__ xl, __hip_bfloat16* __restrict__ xr)
{
    proj_body16(blockIdx.x * 16, threadIdx.x, x, wswz, bl, br, xl, xr);
}

// ---------------------------------------------------------------------------
// Fused attention + aggregation (R8 re-laned layout, depth-2 pipeline).
// R11 (F16=true): xr/q rows are f16; score math in packed f16
// (v_pk_add/mul/max_f16) + v_dot2_f32_f16 accumulate — 8 ops per item
// vs 19 in the f32 path; acc stays f32.  F16=false: legacy bf16/f32 path.
// ---------------------------------------------------------------------------
template<bool F16>
__global__ __launch_bounds__(256) void agg_kernel(
    const char* __restrict__ xrb,      // rows: f16 (F16) or bf16 (!F16), 256 B
    const char* __restrict__ qb,       // q: f16 rows 256B (F16) or f32 rows (legacy)
    const char* __restrict__ degbase, int degpacked,
    const uint16_t* __restrict__ csr, int ldcsr, int cap,
    const float* __restrict__ att, const float* __restrict__ bias,
    float* out)
{
    int n = blockIdx.x * 4 + (threadIdx.x >> 6);
    if (n >= N_NODES) return;
    int lane = threadIdx.x & 63;
    int lpos = lane & 31;
    bool isB = lane >= 32;
    uint32_t voff = (uint32_t)lpos * 8u;

    const float L2E = 1.44269504088896f;   // exp2 prescale (exp(t)=exp2(t*log2e))
    f32x4 av4 = *(const f32x4*)(att + lpos * 4);
    f32x4 bv4 = *(const f32x4*)(bias + lpos * 4);

    // per-variant operand registers (unused set optimized away)
    f32x2 q01{}, q23{}, a01{}, a23{};
    h2 q01h{}, q23h{}, a01h{}, a23h{}, ns2{};
    if constexpr (F16) {
        uint2 qa = *(const uint2*)(qb + (size_t)n * 256 + voff);
        q01h = __builtin_bit_cast(h2, qa.x);
        q23h = __builtin_bit_cast(h2, qa.y);
        a01h[0] = (_Float16)(av4[0] * L2E); a01h[1] = (_Float16)(av4[1] * L2E);
        a23h[0] = (_Float16)(av4[2] * L2E); a23h[1] = (_Float16)(av4[3] * L2E);
        ns2[0] = (_Float16)NEG_SLOPE; ns2[1] = (_Float16)NEG_SLOPE;
    } else {
        f32x4 qv4 = *(const f32x4*)((const float*)qb + (size_t)n * IN_CH + lpos * 4);
        q01[0] = qv4[0]; q01[1] = qv4[1];
        q23[0] = qv4[2]; q23[1] = qv4[3];
        a01[0] = av4[0] * L2E; a01[1] = av4[1] * L2E;
        a23[0] = av4[2] * L2E; a23[1] = av4[3] * L2E;
    }

    int deg;
    if (degpacked) {
        uint32_t pk = ((const uint32_t*)degbase)[n >> 2];
        deg = (int)((pk >> ((n & 3) * 8)) & 255u);
    } else {
        deg = ((const int*)degbase)[n];
    }
    deg = min(deg, cap);
    deg = min(deg, 63);                  // items = deg+1 <= 64 (readlane bound)

    // item registry: lane k holds item k's row BYTE OFFSET (k=0 -> self)
    const uint16_t* lst = csr + (size_t)n * ldcsr;
    int idxreg = (int)lst[min(max(lane - 1, 0), cap - 1)];
    idxreg = (lane == 0) ? n : idxreg;
    idxreg <<= 8;                        // pre-shift: row byte offset

    int last = deg;                      // highest valid item index
    int FP   = (deg + 1) >> 1;           // full pairs
    int ODD  = (deg + 1) & 1;

    float lsum = 0.f;
    f32x2 acc0 = {0.f, 0.f}, acc1 = {0.f, 0.f};

#define PAIR_LOAD(p, udst) { \
        int sa_ = __builtin_amdgcn_readlane(idxreg, min(2 * (p), last)); \
        int sb_ = __builtin_amdgcn_readlane(idxreg, min(2 * (p) + 1, last)); \
        uint32_t vs_ = (uint32_t)(isB ? sb_ : sa_); \
        udst = *(const uint2*)(xrb + vs_ + voff); \
    }

#define PAIR_EVAL(u, MASKED) { \
        float t_; f32x2 c0_, c1_; \
        if constexpr (F16) { \
            h2 ch0_ = __builtin_bit_cast(h2, (u).x); \
            h2 ch1_ = __builtin_bit_cast(h2, (u).y); \
            h2 s0_ = q01h + ch0_, s1_ = q23h + ch1_; \
            h2 l0_ = h2max(s0_, s0_ * ns2), l1_ = h2max(s1_, s1_ * ns2); \
            t_ = fdot2h(l1_, a23h, fdot2h(l0_, a01h, 0.f)); \
            c0_[0] = (float)ch0_[0]; c0_[1] = (float)ch0_[1]; \
            c1_[0] = (float)ch1_[0]; c1_[1] = (float)ch1_[1]; \
        } else { \
            c0_[0] = bf_lo((u).x); c0_[1] = bf_hi((u).x); \
            c1_[0] = bf_lo((u).y); c1_[1] = bf_hi((u).y); \
            f32x2 r0_ = lrelu2(q01 + c0_) * a01; \
            f32x2 r1_ = lrelu2(q23 + c1_) * a23; \
            t_ = (r0_[0] + r0_[1]) + (r1_[0] + r1_[1]); \
        } \
        t_ += DPPADD(t_, 0xB1);   /* quad_perm[1,0,3,2]: xor1 */ \
        t_ += DPPADD(t_, 0x4E);   /* quad_perm[2,3,0,1]: xor2 */ \
        t_ += DPPADD(t_, 0x141);  /* row_half_mirror: 8-lane (32ch=1 head) sum */ \
        float w_ = __builtin_amdgcn_exp2f(t_); \
        if (MASKED) w_ = isB ? 0.f : w_; \
        lsum += w_; \
        acc0 += w_ * c0_; \
        acc1 += w_ * c1_; \
    }

    // depth-2 pipeline over pairs (clamped indices -> extra loads are valid rows)
    uint2 u0, u1;
    PAIR_LOAD(0, u0);
    PAIR_LOAD(1, u1);
    for (int p = 0; p < FP; ++p) {
        uint2 u2;
        PAIR_LOAD(p + 2, u2);
        PAIR_EVAL(u0, false);
        u0 = u1; u1 = u2;
    }
    if (ODD) {
        PAIR_EVAL(u0, true);             // tail item: half B duplicates -> zeroed
    }

    // combine the two wave-halves (disjoint item sets, same channels)
    lsum    += __shfl_xor(lsum,    32);
    acc0[0] += __shfl_xor(acc0[0], 32);
    acc0[1] += __shfl_xor(acc0[1], 32);
    acc1[0] += __shfl_xor(acc1[0], 32);
    acc1[1] += __shfl_xor(acc1[1], 32);

    float inv = 1.f / lsum;
    if (lane < 32) {
        f32x4 ov;
        ov[0] = acc0[0] * inv + bv4[0];
        ov[1] = acc0[1] * inv + bv4[1];
        ov[2] = acc1[0] * inv + bv4[2];
        ov[3] = acc1[1] * inv + bv4[3];
        *(f32x4*)(out + (size_t)n * IN_CH + lpos * 4) = ov;
    }
#undef PAIR_LOAD
#undef PAIR_EVAL
}

extern "C" void kernel_launch(void* const* d_in, const int* in_sizes, int n_in,
                              void* d_out, int out_size, void* d_ws, size_t ws_size,
                              hipStream_t stream) {
    const float* x    = (const float*)d_in[0];
    const int*   ei   = (const int*)d_in[1];
    const float* Wl   = (const float*)d_in[2];
    const float* bl   = (const float*)d_in[3];
    const float* Wr   = (const float*)d_in[4];
    const float* br   = (const float*)d_in[5];
    const float* att  = (const float*)d_in[6];
    const float* bias = (const float*)d_in[7];
    float* out = (float*)d_out;

    // workspace layout (radix mode, bytes):
    //   xr     : [0, 12.8M)              f16 [N, 128]   (R11: was bf16)
    //   xl     : [12.8M, 25.6M)          f16 [N, 128]
    //   wswz   : [25.6M, +65536)         bf16 [4096*8]
    //   degs   : [25665536, +50176)      u8 packed degrees (196*64 u32)
    //   bcnt   : [25715712, +784)        u32 [196] (ends 25716496)
    //   region : [25716736, +196*24576)  bins overlaid with csr slabs
    char* ws = (char*)d_ws;

    const size_t XL_OFF   = 12800000;
    const size_t WSWZ_OFF = 25600000;
    const size_t DEGS_OFF = 25665536;
    const size_t BCNT_OFF = 25715712;
    const size_t REG_OFF  = 25716736;    // >= BCNT_OFF+784 = 25716496, 512-aligned
    const size_t NEED     = REG_OFF + (size_t)NBUCK * BSTRIDE;   // 30,533,632

    if (ws_size >= NEED) {
        _Float16* xr = (_Float16*)(ws);
        _Float16* xl = (_Float16*)(ws + XL_OFF);
        __hip_bfloat16* wswz = (__hip_bfloat16*)(ws + WSWZ_OFF);
        uint32_t* degs   = (uint32_t*)(ws + DEGS_OFF);
        uint32_t* bcnt   = (uint32_t*)(ws + BCNT_OFF);
        char*     region = ws + REG_OFF;

        prep_kernel<<<64, 256, 0, stream>>>(Wl, Wr, wswz, (int*)bcnt, NBUCK);
        proj_fill<<<FILLB + PROJ32B, 256, 0, stream>>>(
            x, wswz, bl, br, xl, xr, ei, bcnt, region);
        csr_build<<<NBUCK, 256, 0, stream>>>(bcnt, region, degs);
        agg_kernel<true><<<N_NODES / 4, 256, 0, stream>>>(
            (const char*)xr, (const char*)xl, (const char*)degs, 1,
            (const uint16_t*)region, CAPR, CAPR, att, bias, out);
    } else {
        // legacy (R4) fallback: xl f32 in d_out, xr bf16, split-array CSR
        const size_t LG_WSWZ = 12800000;
        const size_t LG_CNT  = 12865536;
        const size_t CSR_BASE = 13065536;
        __hip_bfloat16* xr   = (__hip_bfloat16*)(ws);
        __hip_bfloat16* wswz = (__hip_bfloat16*)(ws + LG_WSWZ);
        int*      cnt = (int*)(ws + LG_CNT);
        uint16_t* csr = (uint16_t*)(ws + CSR_BASE);
        long long avail = (ws_size > CSR_BASE) ? (long long)(ws_size - CSR_BASE) : 0;
        int cap = (int)(avail / ((long long)N_NODES * 2));
        if (cap > 64) cap = 64;
        if (cap < 1)  cap = 1;

        prep_kernel<<<64, 256, 0, stream>>>(Wl, Wr, wswz, cnt, N_NODES);
        fill_kernel<<<FILL_BLOCKS, 256, 0, stream>>>(ei, cap, cnt, csr);
        proj_kernel<<<N_NODES / 16, 256, 0, stream>>>(x, wswz, bl, br, out, xr);
        agg_kernel<false><<<N_NODES / 4, 256, 0, stream>>>(
            (const char*)xr, (const char*)out, (const char*)cnt, 0,
            csr, cap, cap, att, bias, out);
    }
}

// Round 12
// 161.326 us; speedup vs baseline: 1.0169x; 1.0019x over previous
//
#include <hip/hip_runtime.h>
#include <hip/hip_bf16.h>
#include <stdint.h>

#define N_NODES 50000
#define N_EDGES 800000
#define IN_CH   128
#define NEG_SLOPE 0.2f

// ---- radix CSR build (R7 geometry, verified) ----
#define NBUCK   196              // bucket = tgt>>8 (256 nodes per bucket)
#define E1      4000             // edges per pass-1 block
#define FILLB   200              // 800000 / 4000
#define BCAP    6144             // u32 records per bucket region (24576/4)
#define BSTRIDE 24576            // bytes per bucket region == 256*48*2 (csr overlay)
#define CAPR    48               // csr slots per node
#define PROJ32B 1563             // ceil(50000/32) 32-row proj blocks
#define TROW    132              // LDS tile row: 128 f16 + 4 pad (264 B)

// ---- legacy fallback (R4) ----
#define E_PER 8
#define FILL_BLOCKS 391

typedef short short8 __attribute__((ext_vector_type(8)));
typedef float f32x4  __attribute__((ext_vector_type(4)));
typedef float f32x2  __attribute__((ext_vector_type(2)));
typedef _Float16 h2  __attribute__((ext_vector_type(2)));

static __device__ __forceinline__ float bf_lo(uint32_t p) { return __uint_as_float(p << 16); }
static __device__ __forceinline__ float bf_hi(uint32_t p) { return __uint_as_float(p & 0xffff0000u); }
static __device__ __forceinline__ uint16_t f_to_bf(float f) {
    uint32_t u = __float_as_uint(f);
    u += 0x7fffu + ((u >> 16) & 1u);   // round-to-nearest-even
    return (uint16_t)(u >> 16);
}

// leaky-relu on a packed f32 pair (legacy agg path)
static __device__ __forceinline__ f32x2 lrelu2(f32x2 x) {
    f32x2 s = x * NEG_SLOPE;
    f32x2 r;
    r[0] = fmaxf(x[0], s[0]);
    r[1] = fmaxf(x[1], s[1]);
    return r;
}

// packed f16 max -> v_pk_max_f16
static __device__ __forceinline__ h2 h2max(h2 a, h2 b) {
#if __has_builtin(__builtin_elementwise_max)
    return __builtin_elementwise_max(a, b);
#else
    h2 r; r[0] = a[0] > b[0] ? a[0] : b[0]; r[1] = a[1] > b[1] ? a[1] : b[1]; return r;
#endif
}
// v_dot2_f32_f16: c + a[0]*b[0] + a[1]*b[1] (f32 accumulate)
static __device__ __forceinline__ float fdot2h(h2 a, h2 b, float c) {
#if __has_builtin(__builtin_amdgcn_fdot2)
    return __builtin_amdgcn_fdot2(a, b, c, false);
#else
    return c + (float)a[0] * (float)b[0] + (float)a[1] * (float)b[1];
#endif
}

// single DPP add step (compiler handles hazards for the builtin form)
#define DPPADD(x, ctrl) __uint_as_float(__builtin_amdgcn_update_dpp(0, __float_as_uint(x), ctrl, 0xf, 0xf, true))

// ---------------------------------------------------------------------------
// Shared bodies
// ---------------------------------------------------------------------------
static __device__ __forceinline__ void wswz_body(
    int t, const float* __restrict__ Wl, const float* __restrict__ Wr,
    __hip_bfloat16* __restrict__ wswz)
{
    int ct = t >> 8, rem = t & 255;
    int ch = rem >> 6, lane = rem & 63;
    int m = lane & 15, quad = lane >> 4;
    const float* W = (ct < 8) ? Wl : Wr;
    int o = ((ct & 7) << 4) + m;
    const float* src = W + (size_t)o * IN_CH + ch * 32 + quad * 8;
    short8 f;
#pragma unroll
    for (int j = 0; j < 8; ++j) f[j] = (short)f_to_bf(src[j]);
    *(short8*)((short*)wswz + (size_t)t * 8) = f;
}

// legacy proj: 16 rows/block (fallback path only; xl f32, xr bf16).
static __device__ __forceinline__ void proj_body16(
    int rowbase, int tid,
    const float* __restrict__ x, const __hip_bfloat16* __restrict__ wswz,
    const float* __restrict__ bl, const float* __restrict__ br,
    float* __restrict__ xl, __hip_bfloat16* __restrict__ xr)
{
    int lane = tid & 63;
    int widx = tid >> 6;              // 0..3: ct group
    int m = lane & 15;
    int quad = lane >> 4;

    short8 afrag[4];
    const float* xrow = x + (size_t)(rowbase + m) * IN_CH;
#pragma unroll
    for (int ch = 0; ch < 4; ++ch) {
        f32x4 p0 = *(const f32x4*)(xrow + ch * 32 + quad * 8);
        f32x4 p1 = *(const f32x4*)(xrow + ch * 32 + quad * 8 + 4);
        short8 f;
#pragma unroll
        for (int j = 0; j < 4; ++j) { f[j] = (short)f_to_bf(p0[j]); f[j + 4] = (short)f_to_bf(p1[j]); }
        afrag[ch] = f;
    }

    const short* wz = (const short*)wswz;
    const float* bv = (widx < 2) ? bl : br;   // wave-uniform
#pragma unroll
    for (int cc = 0; cc < 4; ++cc) {
        int ct = widx * 4 + cc;
        int o = ((ct & 7) << 4) + m;
        f32x4 acc = {0.f, 0.f, 0.f, 0.f};
#pragma unroll
        for (int ch = 0; ch < 4; ++ch) {
            short8 bfrag = *(const short8*)(wz + ((size_t)(ct * 4 + ch) * 64 + lane) * 8);
            acc = __builtin_amdgcn_mfma_f32_16x16x32_bf16(afrag[ch], bfrag, acc, 0, 0, 0);
        }
        float bias_v = bv[o];
        // D layout: row = quad*4 + r, col = m   [m89-verified]
        if (widx < 2) {
#pragma unroll
            for (int r = 0; r < 4; ++r)
                xl[(size_t)(rowbase + quad * 4 + r) * IN_CH + o] = acc[r] + bias_v;
        } else {
#pragma unroll
            for (int r = 0; r < 4; ++r)
                xr[(size_t)(rowbase + quad * 4 + r) * IN_CH + o] = __float2bfloat16(acc[r] + bias_v);
        }
    }
}

// R12 proj: 32 rows/block; fragments go to an LDS tile (row-padded, conflict
// free: quads land on disjoint bank octets), then a cooperative epilogue
// stores full 256-B row segments (16 thr x 16 B per row) — store
// transactions /8 vs the direct 2B-per-lane fragment stores.
static __device__ __forceinline__ void proj_body32(
    int rowbase, int tid,
    const float* __restrict__ x, const __hip_bfloat16* __restrict__ wswz,
    const float* __restrict__ bl, const float* __restrict__ br,
    _Float16* __restrict__ xl, _Float16* __restrict__ xr,
    _Float16* __restrict__ tiles /* [2][32][TROW] LDS */)
{
    int lane = tid & 63;
    int widx = tid >> 6;              // 0..3: ct group
    int m = lane & 15;
    int quad = lane >> 4;
    bool t1 = (rowbase + 16 < N_NODES);   // second A-tile valid

    short8 af0[4], af1[4];
    const float* xrow0 = x + (size_t)(rowbase + m) * IN_CH;
#pragma unroll
    for (int ch = 0; ch < 4; ++ch) {
        f32x4 p0 = *(const f32x4*)(xrow0 + ch * 32 + quad * 8);
        f32x4 p1 = *(const f32x4*)(xrow0 + ch * 32 + quad * 8 + 4);
        short8 f;
#pragma unroll
        for (int j = 0; j < 4; ++j) { f[j] = (short)f_to_bf(p0[j]); f[j + 4] = (short)f_to_bf(p1[j]); }
        af0[ch] = f;
    }
    if (t1) {
        const float* xrow1 = x + (size_t)(rowbase + 16 + m) * IN_CH;
#pragma unroll
        for (int ch = 0; ch < 4; ++ch) {
            f32x4 p0 = *(const f32x4*)(xrow1 + ch * 32 + quad * 8);
            f32x4 p1 = *(const f32x4*)(xrow1 + ch * 32 + quad * 8 + 4);
            short8 f;
#pragma unroll
            for (int j = 0; j < 4; ++j) { f[j] = (short)f_to_bf(p0[j]); f[j + 4] = (short)f_to_bf(p1[j]); }
            af1[ch] = f;
        }
    }

    const short* wz = (const short*)wswz;
    const float* bv = (widx < 2) ? bl : br;   // wave-uniform
    _Float16* tbase = tiles + (size_t)(widx >> 1) * 32 * TROW;
#pragma unroll
    for (int cc = 0; cc < 4; ++cc) {
        int ct = widx * 4 + cc;
        int o = ((ct & 7) << 4) + m;
        f32x4 acc0 = {0.f, 0.f, 0.f, 0.f};
        f32x4 acc1 = {0.f, 0.f, 0.f, 0.f};
#pragma unroll
        for (int ch = 0; ch < 4; ++ch) {
            short8 bfrag = *(const short8*)(wz + ((size_t)(ct * 4 + ch) * 64 + lane) * 8);
            acc0 = __builtin_amdgcn_mfma_f32_16x16x32_bf16(af0[ch], bfrag, acc0, 0, 0, 0);
            if (t1)
                acc1 = __builtin_amdgcn_mfma_f32_16x16x32_bf16(af1[ch], bfrag, acc1, 0, 0, 0);
        }
        float bias_v = bv[o];
        // D layout: row = quad*4 + r, col = m   [m89-verified]
#pragma unroll
        for (int r = 0; r < 4; ++r)
            tbase[(quad * 4 + r) * TROW + o] = (_Float16)(acc0[r] + bias_v);
        if (t1) {
#pragma unroll
            for (int r = 0; r < 4; ++r)
                tbase[(16 + quad * 4 + r) * TROW + o] = (_Float16)(acc1[r] + bias_v);
        }
    }
    __syncthreads();

    // cooperative epilogue: 16 threads x 16 B per row -> full 256-B segments
    int row = tid >> 4;              // 0..15
    int off = (tid & 15) * 8;        // f16 elements (16 B)
    int nrep = t1 ? 2 : 1;
#pragma unroll
    for (int tile = 0; tile < 2; ++tile) {
        _Float16* dst = tile ? xr : xl;
        const _Float16* tb = tiles + (size_t)tile * 32 * TROW;
        for (int rep = 0; rep < nrep; ++rep) {
            int rr = row + rep * 16;
            uint4 v = *(const uint4*)(tb + rr * TROW + off);
            *(uint4*)(dst + (size_t)(rowbase + rr) * IN_CH + off) = v;
        }
    }
}

// ---------------------------------------------------------------------------
// prep: wswz swizzle + zero zn ints at z (bucket counters OR legacy cnt).
// ---------------------------------------------------------------------------
__global__ __launch_bounds__(256) void prep_kernel(
    const float* __restrict__ Wl, const float* __restrict__ Wr,
    __hip_bfloat16* __restrict__ wswz, int* __restrict__ z, int zn)
{
    int t = blockIdx.x * 256 + threadIdx.x;
    if (t < 4096) wswz_body(t, Wl, Wr, wswz);
    for (int i = t; i < zn; i += 64 * 256) z[i] = 0;
}

// ---------------------------------------------------------------------------
// K1: fused proj + pass-1 binning.  LDS is a UNION: fill blocks use sorted[],
// proj blocks use tiles[] (disjoint branches, no aliasing within a block).
// ---------------------------------------------------------------------------
__global__ __launch_bounds__(256) void proj_fill(
    const float* __restrict__ x, const __hip_bfloat16* __restrict__ wswz,
    const float* __restrict__ bl, const float* __restrict__ br,
    _Float16* __restrict__ xl, _Float16* __restrict__ xr,
    const int* __restrict__ ei, uint32_t* __restrict__ bcnt,
    char* __restrict__ region)
{
    __shared__ union U {
        uint32_t sorted[E1];                  // 16000 B (fill blocks)
        _Float16 tiles[2 * 32 * TROW];        // 16896 B (proj blocks)
    } u;
    __shared__ uint32_t s_hist[NBUCK], s_lstart[NBUCK], s_loc[NBUCK], s_gbase[NBUCK];
    __shared__ uint32_t s_T;

    if (blockIdx.x >= FILLB) {
        proj_body32((blockIdx.x - FILLB) * 32, threadIdx.x, x, wswz, bl, br,
                    xl, xr, u.tiles);
        return;
    }

    int tid = threadIdx.x;
    int fb = blockIdx.x;
    for (int i = tid; i < NBUCK; i += 256) s_hist[i] = 0;
    __syncthreads();

    const uint32_t* eiw = (const uint32_t*)ei;
    bool zlo = (eiw[2 * (tid & 63) + 1] == 0u);
    bool is64 = __popcll(__ballot(zlo)) >= 32;
    int e0 = fb * E1;

    // pass A: histogram (LDS atomics only)
    for (int k = tid; k < E1; k += 256) {
        int e = e0 + k;
        int s = is64 ? (int)eiw[2 * (size_t)e] : ei[e];
        int t = is64 ? (int)eiw[2 * ((size_t)N_EDGES + e)] : ei[N_EDGES + e];
        if ((unsigned)s < N_NODES && (unsigned)t < N_NODES)
            atomicAdd(&s_hist[t >> 8], 1u);
    }
    __syncthreads();

    if (tid < NBUCK) s_gbase[tid] = atomicAdd(&bcnt[tid], s_hist[tid]);  // 196 global atomics
    if (tid == 0) {
        uint32_t acc = 0;
        for (int i = 0; i < NBUCK; ++i) { s_lstart[i] = acc; acc += s_hist[i]; }
        s_T = acc;
    }
    __syncthreads();
    if (tid < NBUCK) s_loc[tid] = s_lstart[tid];
    __syncthreads();

    // pass B: scatter into LDS, sorted by bucket (record = tgt<<16 | src)
    for (int k = tid; k < E1; k += 256) {
        int e = e0 + k;
        int s = is64 ? (int)eiw[2 * (size_t)e] : ei[e];
        int t = is64 ? (int)eiw[2 * ((size_t)N_EDGES + e)] : ei[N_EDGES + e];
        if ((unsigned)s < N_NODES && (unsigned)t < N_NODES) {
            uint32_t r = atomicAdd(&s_loc[t >> 8], 1u);
            u.sorted[r] = ((uint32_t)t << 16) | (uint32_t)s;
        }
    }
    __syncthreads();

    // pass C: stream out, per-bucket contiguous segments (coalesced)
    int T = (int)s_T;
    for (int k = tid; k < T; k += 256) {
        uint32_t v = u.sorted[k];
        uint32_t key = v >> 24;                        // tgt>>8
        uint32_t g = s_gbase[key] + (uint32_t)k - s_lstart[key];
        if (g < BCAP)
            ((uint32_t*)(region + (size_t)key * BSTRIDE))[g] = v;
    }
}

// ---------------------------------------------------------------------------
// K2: per-bucket CSR build (R7, verified).
// ---------------------------------------------------------------------------
__global__ __launch_bounds__(256) void csr_build(
    const uint32_t* __restrict__ bcnt, char* __restrict__ region,
    uint32_t* __restrict__ degs32)
{
    __shared__ uint16_t slab[256 * CAPR];   // 24576 B
    __shared__ uint32_t lcnt[256];
    int b = blockIdx.x, tid = threadIdx.x;
    lcnt[tid] = 0;
    __syncthreads();

    uint32_t* reg = (uint32_t*)(region + (size_t)b * BSTRIDE);
    int M = min((int)bcnt[b], BCAP);
    for (int k = tid; k < M; k += 256) {
        uint32_t v = reg[k];
        int node = (int)((v >> 16) & 255u);
        uint32_t pos = atomicAdd(&lcnt[node], 1u);
        if (pos < CAPR) slab[node * CAPR + pos] = (uint16_t)(v & 0xffffu);
    }
    __syncthreads();

    // slab -> global (overlay; all of reg was read before this barrier)
    const uint32_t* sw = (const uint32_t*)slab;
    for (int j = tid; j < (256 * CAPR / 2); j += 256) reg[j] = sw[j];
    if (tid < 64) {
        uint32_t p = 0;
#pragma unroll
        for (int q = 0; q < 4; ++q) {
            uint32_t d = min(lcnt[tid * 4 + q], (uint32_t)CAPR);
            p |= d << (q * 8);
        }
        degs32[b * 64 + tid] = p;
    }
}

// ---------------------------------------------------------------------------
// Legacy fill (R4): bucket-CSR via per-edge global atomics (fallback only).
// ---------------------------------------------------------------------------
__global__ __launch_bounds__(256) void fill_kernel(
    const int* __restrict__ ei, int cap,
    int* __restrict__ cnt, uint16_t* __restrict__ csr)
{
    const uint32_t* eiw = (const uint32_t*)ei;
    bool z = (eiw[2 * (threadIdx.x & 63) + 1] == 0u);
    bool is64 = __popcll(__ballot(z)) >= 32;

    int tid = blockIdx.x * 256 + threadIdx.x;
    int e0 = tid * E_PER;
    if (e0 >= N_EDGES) return;

    int src[E_PER], tgt[E_PER];
    if (is64) {
        const int4* ps = (const int4*)(eiw + 2 * (size_t)e0);
        const int4* pt = (const int4*)(eiw + 2 * ((size_t)N_EDGES + e0));
#pragma unroll
        for (int k = 0; k < 4; ++k) {
            int4 s = ps[k], t = pt[k];
            src[2 * k] = s.x; src[2 * k + 1] = s.z;
            tgt[2 * k] = t.x; tgt[2 * k + 1] = t.z;
        }
    } else {
        const int4* ps = (const int4*)(ei + e0);
        const int4* pt = (const int4*)(ei + N_EDGES + e0);
#pragma unroll
        for (int k = 0; k < 2; ++k) {
            int4 s = ps[k], t = pt[k];
            src[4 * k] = s.x; src[4 * k + 1] = s.y; src[4 * k + 2] = s.z; src[4 * k + 3] = s.w;
            tgt[4 * k] = t.x; tgt[4 * k + 1] = t.y; tgt[4 * k + 2] = t.z; tgt[4 * k + 3] = t.w;
        }
    }

    int pos[E_PER];
#pragma unroll
    for (int k = 0; k < E_PER; ++k) {
        bool ok = (unsigned)src[k] < N_NODES && (unsigned)tgt[k] < N_NODES;
        pos[k] = ok ? atomicAdd(&cnt[tgt[k]], 1) : cap;
    }
#pragma unroll
    for (int k = 0; k < E_PER; ++k)
        if (pos[k] < cap) csr[(size_t)tgt[k] * cap + pos[k]] = (uint16_t)src[k];
}

// Legacy standalone proj (xl = f32 into d_out, xr = bf16).
__global__ __launch_bounds__(256) void proj_kernel(
    const float* __restrict__ x, const __hip_bfloat16* __restrict__ wswz,
    const float* __restrict__ bl, const float* __restrict__ br,
    float* __restrict__ xl, __hip_bfloat16* __restrict__ xr)
{
    proj_body16(blockIdx.x * 16, threadIdx.x, x, wswz, bl, br, xl, xr);
}

// ---------------------------------------------------------------------------
// Fused attention + aggregation (R8 re-laned layout, depth-2 pipeline).
// F16=true: f16 rows, packed-f16 score math + fdot2; R12: readlane clamps
// removed (garbage registry u16 -> byte offsets <= 16.78 MB, always inside
// the >= 30.5 MB radix workspace; garbage pairs masked/never-evaluated).
// F16=false: legacy bf16/f32 path, clamps kept (smaller ws).
// ---------------------------------------------------------------------------
template<bool F16>
__global__ __launch_bounds__(256) void agg_kernel(
    const char* __restrict__ xrb,      // rows: f16 (F16) or bf16 (!F16), 256 B
    const char* __restrict__ qb,       // q: f16 rows 256B (F16) or f32 rows (legacy)
    const char* __restrict__ degbase, int degpacked,
    const uint16_t* __restrict__ csr, int ldcsr, int cap,
    const float* __restrict__ att, const float* __restrict__ bias,
    float* out)
{
    int n = blockIdx.x * 4 + (threadIdx.x >> 6);
    if (n >= N_NODES) return;
    int lane = threadIdx.x & 63;
    int lpos = lane & 31;
    bool isB = lane >= 32;
    uint32_t voff = (uint32_t)lpos * 8u;

    const float L2E = 1.44269504088896f;   // exp2 prescale (exp(t)=exp2(t*log2e))
    f32x4 av4 = *(const f32x4*)(att + lpos * 4);
    f32x4 bv4 = *(const f32x4*)(bias + lpos * 4);

    // per-variant operand registers (unused set optimized away)
    f32x2 q01{}, q23{}, a01{}, a23{};
    h2 q01h{}, q23h{}, a01h{}, a23h{}, ns2{};
    if constexpr (F16) {
        uint2 qa = *(const uint2*)(qb + (size_t)n * 256 + voff);
        q01h = __builtin_bit_cast(h2, qa.x);
        q23h = __builtin_bit_cast(h2, qa.y);
        a01h[0] = (_Float16)(av4[0] * L2E); a01h[1] = (_Float16)(av4[1] * L2E);
        a23h[0] = (_Float16)(av4[2] * L2E); a23h[1] = (_Float16)(av4[3] * L2E);
        ns2[0] = (_Float16)NEG_SLOPE; ns2[1] = (_Float16)NEG_SLOPE;
    } else {
        f32x4 qv4 = *(const f32x4*)((const float*)qb + (size_t)n * IN_CH + lpos * 4);
        q01[0] = qv4[0]; q01[1] = qv4[1];
        q23[0] = qv4[2]; q23[1] = qv4[3];
        a01[0] = av4[0] * L2E; a01[1] = av4[1] * L2E;
        a23[0] = av4[2] * L2E; a23[1] = av4[3] * L2E;
    }

    int deg;
    if (degpacked) {
        uint32_t pk = ((const uint32_t*)degbase)[n >> 2];
        deg = (int)((pk >> ((n & 3) * 8)) & 255u);
    } else {
        deg = ((const int*)degbase)[n];
    }
    deg = min(deg, cap);
    deg = min(deg, 59);                  // readlane idx <= deg+4 <= 63

    // item registry: lane k holds item k's row BYTE OFFSET (k=0 -> self)
    const uint16_t* lst = csr + (size_t)n * ldcsr;
    int idxreg = (int)lst[min(max(lane - 1, 0), cap - 1)];
    idxreg = (lane == 0) ? n : idxreg;
    idxreg <<= 8;                        // pre-shift: row byte offset

    int last = deg;                      // highest valid item index
    int FP   = (deg + 1) >> 1;           // full pairs
    int ODD  = (deg + 1) & 1;

    float lsum = 0.f;
    f32x2 acc0 = {0.f, 0.f}, acc1 = {0.f, 0.f};

    // F16 path: no clamp (garbage offsets in-bounds, garbage lanes masked);
    // legacy path: clamp to last (smaller workspace).
#define RLIDX(k) (F16 ? (k) : min((k), last))
#define PAIR_LOAD(p, udst) { \
        int sa_ = __builtin_amdgcn_readlane(idxreg, RLIDX(2 * (p))); \
        int sb_ = __builtin_amdgcn_readlane(idxreg, RLIDX(2 * (p) + 1)); \
        uint32_t vs_ = (uint32_t)(isB ? sb_ : sa_); \
        udst = *(const uint2*)(xrb + vs_ + voff); \
    }

#define PAIR_EVAL(u, MASKED) { \
        float t_; f32x2 c0_, c1_; \
        if constexpr (F16) { \
            h2 ch0_ = __builtin_bit_cast(h2, (u).x); \
            h2 ch1_ = __builtin_bit_cast(h2, (u).y); \
            h2 s0_ = q01h + ch0_, s1_ = q23h + ch1_; \
            h2 l0_ = h2max(s0_, s0_ * ns2), l1_ = h2max(s1_, s1_ * ns2); \
            t_ = fdot2h(l1_, a23h, fdot2h(l0_, a01h, 0.f)); \
            c0_[0] = (float)ch0_[0]; c0_[1] = (float)ch0_[1]; \
            c1_[0] = (float)ch1_[0]; c1_[1] = (float)ch1_[1]; \
        } else { \
            c0_[0] = bf_lo((u).x); c0_[1] = bf_hi((u).x); \
            c1_[0] = bf_lo((u).y); c1_[1] = bf_hi((u).y); \
            f32x2 r0_ = lrelu2(q01 + c0_) * a01; \
            f32x2 r1_ = lrelu2(q23 + c1_) * a23; \
            t_ = (r0_[0] + r0_[1]) + (r1_[0] + r1_[1]); \
        } \
        t_ += DPPADD(t_, 0xB1);   /* quad_perm[1,0,3,2]: xor1 */ \
        t_ += DPPADD(t_, 0x4E);   /* quad_perm[2,3,0,1]: xor2 */ \
        t_ += DPPADD(t_, 0x141);  /* row_half_mirror: 8-lane (32ch) sum */ \
        float w_ = __builtin_amdgcn_exp2f(t_); \
        if (MASKED) w_ = isB ? 0.f : w_; \
        lsum += w_; \
        acc0 += w_ * c0_; \
        acc1 += w_ * c1_; \
    }

    // depth-2 pipeline over pairs (prefetch beyond end: in-bounds, unused)
    uint2 u0, u1;
    PAIR_LOAD(0, u0);
    PAIR_LOAD(1, u1);
    for (int p = 0; p < FP; ++p) {
        uint2 u2;
        PAIR_LOAD(p + 2, u2);
        PAIR_EVAL(u0, false);
        u0 = u1; u1 = u2;
    }
    if (ODD) {
        PAIR_EVAL(u0, true);             // tail item: B half garbage -> zeroed
    }

    // combine the two wave-halves (disjoint item sets, same channels)
    lsum    += __shfl_xor(lsum,    32);
    acc0[0] += __shfl_xor(acc0[0], 32);
    acc0[1] += __shfl_xor(acc0[1], 32);
    acc1[0] += __shfl_xor(acc1[0], 32);
    acc1[1] += __shfl_xor(acc1[1], 32);

    float inv = 1.f / lsum;
    if (lane < 32) {
        f32x4 ov;
        ov[0] = acc0[0] * inv + bv4[0];
        ov[1] = acc0[1] * inv + bv4[1];
        ov[2] = acc1[0] * inv + bv4[2];
        ov[3] = acc1[1] * inv + bv4[3];
        *(f32x4*)(out + (size_t)n * IN_CH + lpos * 4) = ov;
    }
#undef PAIR_LOAD
#undef PAIR_EVAL
#undef RLIDX
}

extern "C" void kernel_launch(void* const* d_in, const int* in_sizes, int n_in,
                              void* d_out, int out_size, void* d_ws, size_t ws_size,
                              hipStream_t stream) {
    const float* x    = (const float*)d_in[0];
    const int*   ei   = (const int*)d_in[1];
    const float* Wl   = (const float*)d_in[2];
    const float* bl   = (const float*)d_in[3];
    const float* Wr   = (const float*)d_in[4];
    const float* br   = (const float*)d_in[5];
    const float* att  = (const float*)d_in[6];
    const float* bias = (const float*)d_in[7];
    float* out = (float*)d_out;

    // workspace layout (radix mode, bytes):
    //   xr     : [0, 12.8M)              f16 [N, 128]
    //   xl     : [12.8M, 25.6M)          f16 [N, 128]
    //   wswz   : [25.6M, +65536)         bf16 [4096*8]
    //   degs   : [25665536, +50176)      u8 packed degrees (196*64 u32)
    //   bcnt   : [25715712, +784)        u32 [196] (ends 25716496)
    //   region : [25716736, +196*24576)  bins overlaid with csr slabs
    char* ws = (char*)d_ws;

    const size_t XL_OFF   = 12800000;
    const size_t WSWZ_OFF = 25600000;
    const size_t DEGS_OFF = 25665536;
    const size_t BCNT_OFF = 25715712;
    const size_t REG_OFF  = 25716736;    // >= BCNT_OFF+784 = 25716496, 512-aligned
    const size_t NEED     = REG_OFF + (size_t)NBUCK * BSTRIDE;   // 30,533,632

    if (ws_size >= NEED) {
        _Float16* xr = (_Float16*)(ws);
        _Float16* xl = (_Float16*)(ws + XL_OFF);
        __hip_bfloat16* wswz = (__hip_bfloat16*)(ws + WSWZ_OFF);
        uint32_t* degs   = (uint32_t*)(ws + DEGS_OFF);
        uint32_t* bcnt   = (uint32_t*)(ws + BCNT_OFF);
        char*     region = ws + REG_OFF;

        prep_kernel<<<64, 256, 0, stream>>>(Wl, Wr, wswz, (int*)bcnt, NBUCK);
        proj_fill<<<FILLB + PROJ32B, 256, 0, stream>>>(
            x, wswz, bl, br, xl, xr, ei, bcnt, region);
        csr_build<<<NBUCK, 256, 0, stream>>>(bcnt, region, degs);
        agg_kernel<true><<<N_NODES / 4, 256, 0, stream>>>(
            (const char*)xr, (const char*)xl, (const char*)degs, 1,
            (const uint16_t*)region, CAPR, CAPR, att, bias, out);
    } else {
        // legacy (R4) fallback: xl f32 in d_out, xr bf16, split-array CSR
        const size_t LG_WSWZ = 12800000;
        const size_t LG_CNT  = 12865536;
        const size_t CSR_BASE = 13065536;
        __hip_bfloat16* xr   = (__hip_bfloat16*)(ws);
        __hip_bfloat16* wswz = (__hip_bfloat16*)(ws + LG_WSWZ);
        int*      cnt = (int*)(ws + LG_CNT);
        uint16_t* csr = (uint16_t*)(ws + CSR_BASE);
        long long avail = (ws_size > CSR_BASE) ? (long long)(ws_size - CSR_BASE) : 0;
        int cap = (int)(avail / ((long long)N_NODES * 2));
        if (cap > 64) cap = 64;
        if (cap < 1)  cap = 1;

        prep_kernel<<<64, 256, 0, stream>>>(Wl, Wr, wswz, cnt, N_NODES);
        fill_kernel<<<FILL_BLOCKS, 256, 0, stream>>>(ei, cap, cnt, csr);
        proj_kernel<<<N_NODES / 16, 256, 0, stream>>>(x, wswz, bl, br, out, xr);
        agg_kernel<false><<<N_NODES / 4, 256, 0, stream>>>(
            (const char*)xr, (const char*)out, (const char*)cnt, 0,
            csr, cap, cap, att, bias, out);
    }
}